// Round 12
// baseline (146.439 us; speedup 1.0000x reference)
//
#include <hip/hip_runtime.h>

#define NN 100000
#define DD 128
#define EE 640000
#define BN_EPS 1e-3f
#define NBLK 391    // ceil(NN/256); also #buckets and #sort blocks
#define NTILE 6250  // NN/16 exactly
#define EPB 1637    // edges per sort block: 391*1637 >= EE

typedef __bf16 bf16x8 __attribute__((ext_vector_type(8)));
typedef float f32x4 __attribute__((ext_vector_type(4)));

// ---- workspace byte offsets ----
#define W1F_OFF 0u
#define W2F_OFF 32768u
#define B1F_OFF 98304u
#define B2F_OFF 98816u
#define T_OFF   99328u
#define DEG_OFF 25699328u
#define OFFS_OFF 26099328u
#define ELIST_OFF 26899328u   // EE int; first 1.23 MB aliases cntg+bofs (dead before p2)
#define CNTG_OFF ELIST_OFF               // 391*391 int
#define BOFS_OFF (ELIST_OFF + 611524u)   // 391*391 int
#define BSUM_OFF 29459328u
#define BOFF_OFF 29461376u
#define AGG_OFF 29464576u     // NN*128 bf16; aliases pairbuf (EE int) before agg runs

// tanh-form gelu; max |err| vs exact ~3e-4 (threshold 9.8e-2)
__device__ __forceinline__ float gelu_fast(float x) {
    float x3 = x * x * x;
    float z2 = 1.5957691216057308f * x + 0.07135481627002407f * x3;
    return x / (1.0f + __expf(-z2));
}

// prep: [0,64) fold_bias | [64,256) fold_w | [256,2756) per-node hist |
//       [2756,3147) sortA: per-block bucket counts (LDS, no global atomics)
__global__ __launch_bounds__(256) void prep_kernel(
    const float* __restrict__ g1, const float* __restrict__ be1,
    const float* __restrict__ m1, const float* __restrict__ v1,
    const float* __restrict__ W1, const float* __restrict__ b1,
    const float* __restrict__ g2, const float* __restrict__ be2,
    const float* __restrict__ m2, const float* __restrict__ v2,
    const float* __restrict__ W2, const float* __restrict__ b2,
    const int* __restrict__ edges,
    __bf16* __restrict__ W1f, __bf16* __restrict__ W2f,
    float* __restrict__ b1f, float* __restrict__ b2f,
    int* __restrict__ deg, int* __restrict__ cntg)
{
    const int blk = blockIdx.x;
    const int t = threadIdx.x;
    if (blk < 64) {
        const int w = (blk * 256 + t) >> 6;
        const int lane = t & 63;
        if (w < 128) {
            float acc = 0.f;
            for (int k = lane; k < 128; k += 64) {
                float s = g1[k] * rsqrtf(v1[k] + BN_EPS);
                float sh = be1[k] - m1[k] * s;
                acc += sh * W1[k * 128 + w];
            }
#pragma unroll
            for (int off = 32; off > 0; off >>= 1) acc += __shfl_down(acc, off);
            if (lane == 0) b1f[w] = acc + b1[w];
        } else {
            const int n = w - 128;
            float acc = 0.f;
            for (int k = lane; k < 256; k += 64) {
                float s = g2[k] * rsqrtf(v2[k] + BN_EPS);
                float sh = be2[k] - m2[k] * s;
                acc += sh * W2[k * 128 + n];
            }
#pragma unroll
            for (int off = 32; off > 0; off >>= 1) acc += __shfl_down(acc, off);
            if (lane == 0) b2f[n] = acc + b2[n];
        }
    } else if (blk < 256) {
        int tid = (blk - 64) * 256 + t;
        if (tid < 16384) {
            int idx = tid;
            int i = idx & 7, l = (idx >> 3) & 63, nt = (idx >> 9) & 7, kt = idx >> 12;
            int k = kt * 32 + (l >> 4) * 8 + i;
            int n = nt * 16 + (l & 15);
            float s = g1[k] * rsqrtf(v1[k] + BN_EPS);
            W1f[idx] = (__bf16)(s * W1[k * 128 + n]);
        } else {
            int idx = tid - 16384;
            int i = idx & 7, l = (idx >> 3) & 63, nt = (idx >> 9) & 7, kt = idx >> 12;
            int n = nt * 16 + (l & 15);
            int row;
            if (kt < 4) {
                row = kt * 32 + (l >> 4) * 8 + i;
            } else {
                int q = (kt - 4) * 32 + (l >> 4) * 8 + i;
                row = 128 + ((q & 7) * 16 + (q >> 3));
            }
            float s = g2[row] * rsqrtf(v2[row] + BN_EPS);
            W2f[idx] = (__bf16)(s * W2[row * 128 + n]);
        }
    } else if (blk < 2756) {
        int e = (blk - 256) * 256 + t;
        if (e < EE) atomicAdd(&deg[edges[e]], 1);
    } else {
        // sortA: count this block's edge slice into 391 LDS bins
        __shared__ int cnt[NBLK];
        const int k = blk - 2756;
        for (int b = t; b < NBLK; b += 256) cnt[b] = 0;
        __syncthreads();
        const int e0 = k * EPB, e1 = min(e0 + EPB, EE);
        for (int e = e0 + t; e < e1; e += 256)
            atomicAdd(&cnt[edges[e] >> 8], 1);
        __syncthreads();
        for (int b = t; b < NBLK; b += 256) cntg[k * NBLK + b] = cnt[b];
    }
}

// [0,391): per-block sum of deg -> bsum | [391,782): sortB per-bucket scan over blocks
__global__ __launch_bounds__(256) void scan_part_kernel(const int* __restrict__ deg,
                                                        int* __restrict__ bsum,
                                                        const int* __restrict__ cntg,
                                                        int* __restrict__ bofs)
{
    const int t = threadIdx.x;
    if (blockIdx.x < NBLK) {
        int i = blockIdx.x * 256 + t;
        int v = (i < NN) ? deg[i] : 0;
#pragma unroll
        for (int off = 32; off > 0; off >>= 1) v += __shfl_down(v, off);
        __shared__ int ws[4];
        if ((t & 63) == 0) ws[t >> 6] = v;
        __syncthreads();
        if (t == 0) bsum[blockIdx.x] = ws[0] + ws[1] + ws[2] + ws[3];
    } else {
        const int b = blockIdx.x - NBLK;
        __shared__ int sp[256];
        int ia = 2 * t, ib = 2 * t + 1;
        int va = (ia < NBLK) ? cntg[ia * NBLK + b] : 0;
        int vb = (ib < NBLK) ? cntg[ib * NBLK + b] : 0;
        sp[t] = va + vb;
        __syncthreads();
        for (int off = 1; off < 256; off <<= 1) {
            int tmp = (t >= off) ? sp[t - off] : 0;
            __syncthreads();
            sp[t] += tmp;
            __syncthreads();
        }
        int pexcl = sp[t] - (va + vb);
        if (ia < NBLK) bofs[b * NBLK + ia] = pexcl;
        if (ib < NBLK) bofs[b * NBLK + ib] = pexcl + va;
    }
}

// single-block exclusive scan of NBLK block sums
__global__ __launch_bounds__(512) void scan_top_kernel(const int* __restrict__ bsum,
                                                       int* __restrict__ boff)
{
    __shared__ int s[512];
    const int t = threadIdx.x;
    int v = (t < NBLK) ? bsum[t] : 0;
    s[t] = v;
    __syncthreads();
    for (int off = 1; off < 512; off <<= 1) {
        int tmp = (t >= off) ? s[t - off] : 0;
        __syncthreads();
        s[t] += tmp;
        __syncthreads();
    }
    if (t < NBLK) boff[t] = s[t] - v;
}

// per-block exclusive scan + block offset -> offs (per-node CSR offsets)
__global__ __launch_bounds__(256) void scan_final_kernel(const int* __restrict__ deg,
                                                         const int* __restrict__ boff,
                                                         int* __restrict__ offs)
{
    __shared__ int s[256];
    const int t = threadIdx.x;
    int i = blockIdx.x * 256 + t;
    int v = (i < NN) ? deg[i] : 0;
    s[t] = v;
    __syncthreads();
    for (int off = 1; off < 256; off <<= 1) {
        int tmp = (t >= off) ? s[t - off] : 0;
        __syncthreads();
        s[t] += tmp;
        __syncthreads();
    }
    int ex = s[t] - v + boff[blockIdx.x];
    if (i < NN) offs[i] = ex;
}

// sortC: scatter edges into bucket-sorted pairbuf; positions precomputed
__global__ __launch_bounds__(256) void sortc_kernel(const int* __restrict__ edges,
                                                    const int* __restrict__ offs,
                                                    const int* __restrict__ bofs,
                                                    int* __restrict__ pairbuf)
{
    __shared__ int cur[NBLK];
    const int k = blockIdx.x, t = threadIdx.x;
    for (int b = t; b < NBLK; b += 256)
        cur[b] = offs[b * 256] + bofs[b * NBLK + k];
    __syncthreads();
    const int e0 = k * EPB, e1 = min(e0 + EPB, EE);
    for (int e = e0 + t; e < e1; e += 256) {
        int dst = edges[e];
        int src = edges[EE + e];
        int pos = atomicAdd(&cur[dst >> 8], 1);
        pairbuf[pos] = (src << 8) | (dst & 255);
    }
}

// p2: one block per 256-node bucket; LDS cursors scatter into per-node segments
__global__ __launch_bounds__(256) void p2_kernel(const int* __restrict__ offs,
                                                 const int* __restrict__ pairbuf,
                                                 int* __restrict__ elist)
{
    __shared__ int cur[256];
    const int b = blockIdx.x, t = threadIdx.x;
    const int nodestart = b * 256;
    const int node = nodestart + t;
    if (node < NN) cur[t] = offs[node];
    __syncthreads();
    const int start = offs[nodestart];
    const int end = (nodestart + 256 >= NN) ? EE : offs[nodestart + 256];
    for (int e = start + t; e < end; e += 256) {
        int item = pairbuf[e];
        int pos = atomicAdd(&cur[item & 255], 1);
        elist[pos] = item >> 8;
    }
}

// t = gelu(X @ W1f + b1f); W1f staged in 32 KB LDS once per block; block = 8
// consecutive 16-row tiles, 4 waves x 2 tiles each (amortizes stage+barrier,
// B reads become ds_read_b128). Contiguous row mapping preserved.
__global__ __launch_bounds__(256) void ffn1_kernel(
    const float* __restrict__ X, const __bf16* __restrict__ W1f,
    const float* __restrict__ b1f, __bf16* __restrict__ T)
{
    __shared__ __bf16 sW[16384];   // 32 KB, identity layout
    const int tid = threadIdx.x;
#pragma unroll
    for (int i = 0; i < 8; ++i) {
        int ch = i * 256 + tid;
        *(bf16x8*)(sW + ch * 8) = *(const bf16x8*)(W1f + (size_t)ch * 8);
    }
    __syncthreads();

    const int wave = tid >> 6;
    const int lane = tid & 63;
    const int c = lane & 15, kh = lane >> 4;
    const int tbase = blockIdx.x * 8;

    float bias[8];
#pragma unroll
    for (int nt = 0; nt < 8; ++nt) bias[nt] = b1f[nt * 16 + c];

#pragma unroll
    for (int s = 0; s < 2; ++s) {
        const int tile = tbase + s * 4 + wave;
        if (tile >= NTILE) break;
        const float* xr = X + (size_t)(tile * 16 + c) * DD + kh * 8;
        f32x4 r0[4], r1[4];
#pragma unroll
        for (int q = 0; q < 4; ++q) {
            r0[q] = *(const f32x4*)(xr + q * 32);
            r1[q] = *(const f32x4*)(xr + q * 32 + 4);
        }
        bf16x8 af[4];
#pragma unroll
        for (int kt = 0; kt < 4; ++kt) {
            bf16x8 fa;
#pragma unroll
            for (int i = 0; i < 4; ++i) { fa[i] = (__bf16)r0[kt][i]; fa[4 + i] = (__bf16)r1[kt][i]; }
            af[kt] = fa;
        }
        f32x4 acc[8] = {};
#pragma unroll
        for (int kt = 0; kt < 4; ++kt)
#pragma unroll
            for (int nt = 0; nt < 8; ++nt) {
                bf16x8 bfr = *(const bf16x8*)(sW + ((kt * 8 + nt) * 64 + lane) * 8);
                acc[nt] = __builtin_amdgcn_mfma_f32_16x16x32_bf16(af[kt], bfr, acc[nt], 0, 0, 0);
            }
#pragma unroll
        for (int r = 0; r < 4; ++r) {
            int row = tile * 16 + kh * 4 + r;
            bf16x8 o;
#pragma unroll
            for (int nt = 0; nt < 8; ++nt)
                o[nt] = (__bf16)gelu_fast(acc[nt][r] + bias[nt]);
            *(bf16x8*)(T + (size_t)row * DD + c * 8) = o;
        }
    }
}

// gather-mean: Agg[node] = mean of T[src] rows (permuted layout kept).
__global__ __launch_bounds__(256) void agg_kernel(
    const __bf16* __restrict__ T, const int* __restrict__ offs,
    const int* __restrict__ deg, const int* __restrict__ elist,
    __bf16* __restrict__ Agg)
{
    int t = blockIdx.x * 256 + threadIdx.x;
    int node = t >> 4, j = t & 15;
    if (node >= NN) return;
    const int beg = offs[node];
    const int d = deg[node];
    const int end = beg + d;
    float acc[8] = {};
    int e = beg;
    for (; e + 3 < end; e += 4) {
        int s0 = elist[e], s1 = elist[e + 1], s2 = elist[e + 2], s3 = elist[e + 3];
        bf16x8 v0 = *(const bf16x8*)(T + (size_t)s0 * DD + j * 8);
        bf16x8 v1 = *(const bf16x8*)(T + (size_t)s1 * DD + j * 8);
        bf16x8 v2 = *(const bf16x8*)(T + (size_t)s2 * DD + j * 8);
        bf16x8 v3 = *(const bf16x8*)(T + (size_t)s3 * DD + j * 8);
#pragma unroll
        for (int i = 0; i < 8; ++i)
            acc[i] += ((float)v0[i] + (float)v1[i]) + ((float)v2[i] + (float)v3[i]);
    }
    for (; e < end; ++e) {
        int s0 = elist[e];
        bf16x8 v0 = *(const bf16x8*)(T + (size_t)s0 * DD + j * 8);
#pragma unroll
        for (int i = 0; i < 8; ++i) acc[i] += (float)v0[i];
    }
    const float inv = 1.0f / fmaxf((float)d, 1.0f);
    bf16x8 o;
#pragma unroll
    for (int i = 0; i < 8; ++i) o[i] = (__bf16)(acc[i] * inv);
    *(bf16x8*)(Agg + (size_t)node * DD + j * 8) = o;
}

// out = gelu([X, Agg] @ W2f + b2f); h = blockIdx parity selects 64-col half
// (32 KB LDS stage); block = 8 consecutive tiles, 4 waves x 2 tiles each.
// Twin block re-reads X/Agg via die-level L3. NT out stores.
__global__ __launch_bounds__(256) void ffn2_kernel(
    const float* __restrict__ X, const __bf16* __restrict__ Agg,
    const __bf16* __restrict__ W2f, const float* __restrict__ b2f,
    float* __restrict__ out)
{
    __shared__ __bf16 sW[16384];   // 32 KB: this half's frags, idx (kt*4+ntp)*64+lane
    const int tid = threadIdx.x;
    const int h = blockIdx.x & 1;
#pragma unroll
    for (int i = 0; i < 8; ++i) {
        int ch = i * 256 + tid;          // [0,2048) chunks of bf16x8
        int f = ch >> 6, l = ch & 63;    // f = kt*4+ntp
        int src = ((f >> 2) * 8 + h * 4 + (f & 3)) * 64 + l;
        *(bf16x8*)(sW + ch * 8) = *(const bf16x8*)(W2f + (size_t)src * 8);
    }
    __syncthreads();

    const int wave = tid >> 6;
    const int lane = tid & 63;
    const int c = lane & 15, kh = lane >> 4;
    const int tbase = (blockIdx.x >> 1) * 8;

    float bias[4];
#pragma unroll
    for (int ntp = 0; ntp < 4; ++ntp) bias[ntp] = b2f[(h * 4 + ntp) * 16 + c];

#pragma unroll
    for (int s = 0; s < 2; ++s) {
        const int tile = tbase + s * 4 + wave;
        if (tile >= NTILE) break;
        const int rowA = tile * 16 + c;
        const float* xr = X + (size_t)rowA * DD + kh * 8;
        const __bf16* ar = Agg + (size_t)rowA * DD + kh * 8;

        f32x4 r0[4], r1[4];
        bf16x8 ag[4];
#pragma unroll
        for (int q = 0; q < 4; ++q) {
            r0[q] = *(const f32x4*)(xr + q * 32);
            r1[q] = *(const f32x4*)(xr + q * 32 + 4);
            ag[q] = *(const bf16x8*)(ar + q * 32);
        }
        bf16x8 a[8];
#pragma unroll
        for (int kt = 0; kt < 4; ++kt) {
            bf16x8 fa;
#pragma unroll
            for (int i = 0; i < 4; ++i) { fa[i] = (__bf16)r0[kt][i]; fa[4 + i] = (__bf16)r1[kt][i]; }
            a[kt] = fa;
            a[4 + kt] = ag[kt];
        }
        f32x4 acc[4] = {};
#pragma unroll
        for (int kt = 0; kt < 8; ++kt)
#pragma unroll
            for (int ntp = 0; ntp < 4; ++ntp) {
                bf16x8 bfr = *(const bf16x8*)(sW + ((kt * 4 + ntp) * 64 + lane) * 8);
                acc[ntp] = __builtin_amdgcn_mfma_f32_16x16x32_bf16(a[kt], bfr, acc[ntp], 0, 0, 0);
            }
#pragma unroll
        for (int r = 0; r < 4; ++r) {
            int row = tile * 16 + kh * 4 + r;
#pragma unroll
            for (int ntp = 0; ntp < 4; ++ntp)
                __builtin_nontemporal_store(gelu_fast(acc[ntp][r] + bias[ntp]),
                                            &out[(size_t)row * DD + (h * 4 + ntp) * 16 + c]);
        }
    }
}

extern "C" void kernel_launch(void* const* d_in, const int* in_sizes, int n_in,
                              void* d_out, int out_size, void* d_ws, size_t ws_size,
                              hipStream_t stream) {
    const float* node_repr = (const float*)d_in[0];
    const int*   edges     = (const int*)d_in[1];
    const float* g1 = (const float*)d_in[2];
    const float* be1 = (const float*)d_in[3];
    const float* m1 = (const float*)d_in[4];
    const float* v1 = (const float*)d_in[5];
    const float* W1 = (const float*)d_in[6];
    const float* b1 = (const float*)d_in[7];
    const float* g2 = (const float*)d_in[8];
    const float* be2 = (const float*)d_in[9];
    const float* m2 = (const float*)d_in[10];
    const float* v2 = (const float*)d_in[11];
    const float* W2 = (const float*)d_in[12];
    const float* b2 = (const float*)d_in[13];

    char* ws = (char*)d_ws;
    __bf16* W1f = (__bf16*)(ws + W1F_OFF);
    __bf16* W2f = (__bf16*)(ws + W2F_OFF);
    float* b1f = (float*)(ws + B1F_OFF);
    float* b2f = (float*)(ws + B2F_OFF);
    __bf16* T  = (__bf16*)(ws + T_OFF);
    int* deg   = (int*)(ws + DEG_OFF);
    int* offs  = (int*)(ws + OFFS_OFF);
    int* elist = (int*)(ws + ELIST_OFF);
    int* cntg  = (int*)(ws + CNTG_OFF);
    int* bofs  = (int*)(ws + BOFS_OFF);
    int* bsum  = (int*)(ws + BSUM_OFF);
    int* boff  = (int*)(ws + BOFF_OFF);
    __bf16* Agg = (__bf16*)(ws + AGG_OFF);
    int* pairbuf = (int*)(ws + AGG_OFF);
    float* out = (float*)d_out;

    hipMemsetAsync(deg, 0, (size_t)NN * 4, stream);

    hipLaunchKernelGGL(prep_kernel, dim3(2756 + NBLK), dim3(256), 0, stream,
                       g1, be1, m1, v1, W1, b1, g2, be2, m2, v2, W2, b2,
                       edges, W1f, W2f, b1f, b2f, deg, cntg);

    hipLaunchKernelGGL(scan_part_kernel, dim3(NBLK * 2), dim3(256), 0, stream,
                       deg, bsum, cntg, bofs);
    hipLaunchKernelGGL(scan_top_kernel, dim3(1), dim3(512), 0, stream, bsum, boff);
    hipLaunchKernelGGL(scan_final_kernel, dim3(NBLK), dim3(256), 0, stream, deg, boff, offs);

    hipLaunchKernelGGL(sortc_kernel, dim3(NBLK), dim3(256), 0, stream,
                       edges, offs, bofs, pairbuf);
    hipLaunchKernelGGL(p2_kernel, dim3(NBLK), dim3(256), 0, stream,
                       offs, pairbuf, elist);

    hipLaunchKernelGGL(ffn1_kernel, dim3((NTILE + 7) / 8), dim3(256), 0, stream,
                       node_repr, W1f, b1f, T);

    hipLaunchKernelGGL(agg_kernel, dim3((NN * 16 + 255) / 256), dim3(256), 0, stream,
                       T, offs, deg, elist, Agg);

    hipLaunchKernelGGL(ffn2_kernel, dim3(((NTILE + 7) / 8) * 2), dim3(256), 0, stream,
                       node_repr, Agg, W2f, b2f, out);
}

// Round 13
// 142.104 us; speedup vs baseline: 1.0305x; 1.0305x over previous
//
#include <hip/hip_runtime.h>

#define NN 100000
#define DD 128
#define EE 640000
#define BN_EPS 1e-3f
#define NBLK 391    // ceil(NN/256); #buckets and #sort blocks
#define NTILE 6250  // NN/16 exactly
#define EPB 1637    // edges per sort block: 391*1637 >= EE

typedef __bf16 bf16x8 __attribute__((ext_vector_type(8)));
typedef float f32x4 __attribute__((ext_vector_type(4)));

// ---- workspace byte offsets ----
#define W1F_OFF 0u
#define W2F_OFF 32768u
#define B1F_OFF 98304u
#define B2F_OFF 98816u
#define T_OFF   99328u
#define DEG_OFF 25699328u
#define OFFS_OFF 26099328u
#define ELIST_OFF 26899328u   // EE int; head aliases cntg+bofs (dead before p2)
#define CNTG_OFF ELIST_OFF               // 391*391 int
#define BOFS_OFF (ELIST_OFF + 611524u)   // 391*391 int
#define BSUM_OFF 29459328u
#define BOFF_OFF 29461376u
#define AGG_OFF 29464576u     // NN*128 bf16; aliases pairbuf (EE int) before agg runs

// tanh-form gelu; max |err| vs exact ~3e-4 (threshold 9.8e-2)
__device__ __forceinline__ float gelu_fast(float x) {
    float x3 = x * x * x;
    float z2 = 1.5957691216057308f * x + 0.07135481627002407f * x3;
    return x / (1.0f + __expf(-z2));
}

// prep: [0,64) fold_bias | [64,256) fold_w | [256,2756) per-node hist |
//       [2756,3147) sortA: per-block bucket counts (LDS, no global atomics)
__global__ __launch_bounds__(256) void prep_kernel(
    const float* __restrict__ g1, const float* __restrict__ be1,
    const float* __restrict__ m1, const float* __restrict__ v1,
    const float* __restrict__ W1, const float* __restrict__ b1,
    const float* __restrict__ g2, const float* __restrict__ be2,
    const float* __restrict__ m2, const float* __restrict__ v2,
    const float* __restrict__ W2, const float* __restrict__ b2,
    const int* __restrict__ edges,
    __bf16* __restrict__ W1f, __bf16* __restrict__ W2f,
    float* __restrict__ b1f, float* __restrict__ b2f,
    int* __restrict__ deg, int* __restrict__ cntg)
{
    const int blk = blockIdx.x;
    const int t = threadIdx.x;
    if (blk < 64) {
        const int w = (blk * 256 + t) >> 6;
        const int lane = t & 63;
        if (w < 128) {
            float acc = 0.f;
            for (int k = lane; k < 128; k += 64) {
                float s = g1[k] * rsqrtf(v1[k] + BN_EPS);
                float sh = be1[k] - m1[k] * s;
                acc += sh * W1[k * 128 + w];
            }
#pragma unroll
            for (int off = 32; off > 0; off >>= 1) acc += __shfl_down(acc, off);
            if (lane == 0) b1f[w] = acc + b1[w];
        } else {
            const int n = w - 128;
            float acc = 0.f;
            for (int k = lane; k < 256; k += 64) {
                float s = g2[k] * rsqrtf(v2[k] + BN_EPS);
                float sh = be2[k] - m2[k] * s;
                acc += sh * W2[k * 128 + n];
            }
#pragma unroll
            for (int off = 32; off > 0; off >>= 1) acc += __shfl_down(acc, off);
            if (lane == 0) b2f[n] = acc + b2[n];
        }
    } else if (blk < 256) {
        int tid = (blk - 64) * 256 + t;
        if (tid < 16384) {
            int idx = tid;
            int i = idx & 7, l = (idx >> 3) & 63, nt = (idx >> 9) & 7, kt = idx >> 12;
            int k = kt * 32 + (l >> 4) * 8 + i;
            int n = nt * 16 + (l & 15);
            float s = g1[k] * rsqrtf(v1[k] + BN_EPS);
            W1f[idx] = (__bf16)(s * W1[k * 128 + n]);
        } else {
            int idx = tid - 16384;
            int i = idx & 7, l = (idx >> 3) & 63, nt = (idx >> 9) & 7, kt = idx >> 12;
            int n = nt * 16 + (l & 15);
            int row;
            if (kt < 4) {
                row = kt * 32 + (l >> 4) * 8 + i;
            } else {
                int q = (kt - 4) * 32 + (l >> 4) * 8 + i;
                row = 128 + ((q & 7) * 16 + (q >> 3));
            }
            float s = g2[row] * rsqrtf(v2[row] + BN_EPS);
            W2f[idx] = (__bf16)(s * W2[row * 128 + n]);
        }
    } else if (blk < 2756) {
        int e = (blk - 256) * 256 + t;
        if (e < EE) atomicAdd(&deg[edges[e]], 1);
    } else {
        __shared__ int cnt[NBLK];
        const int k = blk - 2756;
        for (int b = t; b < NBLK; b += 256) cnt[b] = 0;
        __syncthreads();
        const int e0 = k * EPB, e1 = min(e0 + EPB, EE);
        for (int e = e0 + t; e < e1; e += 256)
            atomicAdd(&cnt[edges[e] >> 8], 1);
        __syncthreads();
        for (int b = t; b < NBLK; b += 256) cntg[k * NBLK + b] = cnt[b];
    }
}

// sortB: bucket b; exclusive scan of cntg[k][b] over k -> bofs; total -> bsum[b]
__global__ __launch_bounds__(256) void sortb_kernel(const int* __restrict__ cntg,
                                                    int* __restrict__ bofs,
                                                    int* __restrict__ bsum)
{
    const int b = blockIdx.x, t = threadIdx.x;
    __shared__ int sp[256];
    int ia = 2 * t, ib = 2 * t + 1;
    int va = (ia < NBLK) ? cntg[ia * NBLK + b] : 0;
    int vb = (ib < NBLK) ? cntg[ib * NBLK + b] : 0;
    sp[t] = va + vb;
    __syncthreads();
    for (int off = 1; off < 256; off <<= 1) {
        int tmp = (t >= off) ? sp[t - off] : 0;
        __syncthreads();
        sp[t] += tmp;
        __syncthreads();
    }
    int pexcl = sp[t] - (va + vb);
    if (ia < NBLK) bofs[b * NBLK + ia] = pexcl;
    if (ib < NBLK) bofs[b * NBLK + ib] = pexcl + va;
    if (t == 255) bsum[b] = sp[255];
}

// single-block exclusive scan of NBLK bucket totals -> boff (bucket bases)
__global__ __launch_bounds__(512) void scan_top_kernel(const int* __restrict__ bsum,
                                                       int* __restrict__ boff)
{
    __shared__ int s[512];
    const int t = threadIdx.x;
    int v = (t < NBLK) ? bsum[t] : 0;
    s[t] = v;
    __syncthreads();
    for (int off = 1; off < 512; off <<= 1) {
        int tmp = (t >= off) ? s[t - off] : 0;
        __syncthreads();
        s[t] += tmp;
        __syncthreads();
    }
    if (t < NBLK) boff[t] = s[t] - v;
}

// sortC: scatter edges into bucket-sorted pairbuf; positions precomputed
__global__ __launch_bounds__(256) void sortc_kernel(const int* __restrict__ edges,
                                                    const int* __restrict__ boff,
                                                    const int* __restrict__ bofs,
                                                    int* __restrict__ pairbuf)
{
    __shared__ int cur[NBLK];
    const int k = blockIdx.x, t = threadIdx.x;
    for (int b = t; b < NBLK; b += 256)
        cur[b] = boff[b] + bofs[b * NBLK + k];
    __syncthreads();
    const int e0 = k * EPB, e1 = min(e0 + EPB, EE);
    for (int e = e0 + t; e < e1; e += 256) {
        int dst = edges[e];
        int src = edges[EE + e];
        int pos = atomicAdd(&cur[dst >> 8], 1);
        pairbuf[pos] = (src << 8) | (dst & 255);
    }
}

// p2: per bucket — LDS scan of deg segment gives per-node offsets (writes offs
// for agg) and seeds cursors; scatter packed edges into per-node elist segments.
__global__ __launch_bounds__(256) void p2_kernel(const int* __restrict__ deg,
                                                 const int* __restrict__ boff,
                                                 const int* __restrict__ pairbuf,
                                                 int* __restrict__ elist,
                                                 int* __restrict__ offs)
{
    __shared__ int s[256];
    __shared__ int cur[256];
    __shared__ int tot;
    const int b = blockIdx.x, t = threadIdx.x;
    const int node = b * 256 + t;
    int v = (node < NN) ? deg[node] : 0;
    s[t] = v;
    __syncthreads();
    for (int off = 1; off < 256; off <<= 1) {
        int tmp = (t >= off) ? s[t - off] : 0;
        __syncthreads();
        s[t] += tmp;
        __syncthreads();
    }
    int ex = s[t] - v + boff[b];
    if (node < NN) offs[node] = ex;
    cur[t] = ex;
    if (t == 255) tot = s[255];
    __syncthreads();
    const int start = boff[b];
    const int end = start + tot;
    for (int e = start + t; e < end; e += 256) {
        int item = pairbuf[e];
        int pos = atomicAdd(&cur[item & 255], 1);
        elist[pos] = item >> 8;
    }
}

// t = gelu(X @ W1f + b1f); W1f staged in 32 KB LDS once per block; block = 8
// consecutive 16-row tiles, 4 waves x 2 tiles (stage+barrier amortized).
__global__ __launch_bounds__(256) void ffn1_kernel(
    const float* __restrict__ X, const __bf16* __restrict__ W1f,
    const float* __restrict__ b1f, __bf16* __restrict__ T)
{
    __shared__ __bf16 sW[16384];   // 32 KB, identity layout
    const int tid = threadIdx.x;
#pragma unroll
    for (int i = 0; i < 8; ++i) {
        int ch = i * 256 + tid;
        *(bf16x8*)(sW + ch * 8) = *(const bf16x8*)(W1f + (size_t)ch * 8);
    }
    __syncthreads();

    const int wave = tid >> 6;
    const int lane = tid & 63;
    const int c = lane & 15, kh = lane >> 4;
    const int tbase = blockIdx.x * 8;

    float bias[8];
#pragma unroll
    for (int nt = 0; nt < 8; ++nt) bias[nt] = b1f[nt * 16 + c];

#pragma unroll
    for (int s = 0; s < 2; ++s) {
        const int tile = tbase + s * 4 + wave;
        if (tile >= NTILE) break;
        const float* xr = X + (size_t)(tile * 16 + c) * DD + kh * 8;
        f32x4 r0[4], r1[4];
#pragma unroll
        for (int q = 0; q < 4; ++q) {
            r0[q] = *(const f32x4*)(xr + q * 32);
            r1[q] = *(const f32x4*)(xr + q * 32 + 4);
        }
        bf16x8 af[4];
#pragma unroll
        for (int kt = 0; kt < 4; ++kt) {
            bf16x8 fa;
#pragma unroll
            for (int i = 0; i < 4; ++i) { fa[i] = (__bf16)r0[kt][i]; fa[4 + i] = (__bf16)r1[kt][i]; }
            af[kt] = fa;
        }
        f32x4 acc[8] = {};
#pragma unroll
        for (int kt = 0; kt < 4; ++kt)
#pragma unroll
            for (int nt = 0; nt < 8; ++nt) {
                bf16x8 bfr = *(const bf16x8*)(sW + ((kt * 8 + nt) * 64 + lane) * 8);
                acc[nt] = __builtin_amdgcn_mfma_f32_16x16x32_bf16(af[kt], bfr, acc[nt], 0, 0, 0);
            }
#pragma unroll
        for (int r = 0; r < 4; ++r) {
            int row = tile * 16 + kh * 4 + r;
            bf16x8 o;
#pragma unroll
            for (int nt = 0; nt < 8; ++nt)
                o[nt] = (__bf16)gelu_fast(acc[nt][r] + bias[nt]);
            *(bf16x8*)(T + (size_t)row * DD + c * 8) = o;
        }
    }
}

// gather-mean: 16 threads/node; ONE coalesced elist load covers 16 edges per
// group, __shfl broadcasts src ids; gathers 4-unrolled for ILP.
__global__ __launch_bounds__(256) void agg_kernel(
    const __bf16* __restrict__ T, const int* __restrict__ offs,
    const int* __restrict__ deg, const int* __restrict__ elist,
    __bf16* __restrict__ Agg)
{
    int t = blockIdx.x * 256 + threadIdx.x;
    int node = t >> 4, j = t & 15;
    if (node >= NN) return;
    const int lane = threadIdx.x & 63;
    const int gbase = lane & 48;
    const int beg = offs[node];
    const int d = deg[node];
    const int end = beg + d;
    float acc[8] = {};
    for (int eb = beg; eb < end; eb += 16) {
        int me = eb + (lane & 15);
        int sv = (me < end) ? elist[me] : 0;
        int cnt = min(end - eb, 16);
        int i = 0;
        for (; i + 3 < cnt; i += 4) {
            int s0 = __shfl(sv, gbase + i);
            int s1 = __shfl(sv, gbase + i + 1);
            int s2 = __shfl(sv, gbase + i + 2);
            int s3 = __shfl(sv, gbase + i + 3);
            bf16x8 v0 = *(const bf16x8*)(T + (size_t)s0 * DD + j * 8);
            bf16x8 v1 = *(const bf16x8*)(T + (size_t)s1 * DD + j * 8);
            bf16x8 v2 = *(const bf16x8*)(T + (size_t)s2 * DD + j * 8);
            bf16x8 v3 = *(const bf16x8*)(T + (size_t)s3 * DD + j * 8);
#pragma unroll
            for (int q = 0; q < 8; ++q)
                acc[q] += ((float)v0[q] + (float)v1[q]) + ((float)v2[q] + (float)v3[q]);
        }
        for (; i < cnt; ++i) {
            int s0 = __shfl(sv, gbase + i);
            bf16x8 v0 = *(const bf16x8*)(T + (size_t)s0 * DD + j * 8);
#pragma unroll
            for (int q = 0; q < 8; ++q) acc[q] += (float)v0[q];
        }
    }
    const float inv = 1.0f / fmaxf((float)d, 1.0f);
    bf16x8 o;
#pragma unroll
    for (int q = 0; q < 8; ++q) o[q] = (__bf16)(acc[q] * inv);
    *(bf16x8*)(Agg + (size_t)node * DD + j * 8) = o;
}

// out = gelu([X, Agg] @ W2f + b2f); R11 form: unit = tile*2+half, both halves
// of a tile in the SAME block (X/Agg L1 reuse); reg ping-pong B prefetch.
__global__ __launch_bounds__(256) void ffn2_kernel(
    const float* __restrict__ X, const __bf16* __restrict__ Agg,
    const __bf16* __restrict__ W2f, const float* __restrict__ b2f,
    float* __restrict__ out)
{
    const int wave = threadIdx.x >> 6;
    const int lane = threadIdx.x & 63;
    const int unit = blockIdx.x * 4 + wave;   // = tile*2 + half
    const int tile = unit >> 1;
    const int h = unit & 1;
    if (tile >= NTILE) return;
    const int c = lane & 15, kh = lane >> 4;

    const int rowA = tile * 16 + c;
    const float* xr = X + (size_t)rowA * DD + kh * 8;
    const __bf16* ar = Agg + (size_t)rowA * DD + kh * 8;

    f32x4 r0[4], r1[4];
    bf16x8 ag[4];
#pragma unroll
    for (int q = 0; q < 4; ++q) {
        r0[q] = *(const f32x4*)(xr + q * 32);
        r1[q] = *(const f32x4*)(xr + q * 32 + 4);
        ag[q] = *(const bf16x8*)(ar + q * 32);
    }
    bf16x8 bp[4], bq[4];
#pragma unroll
    for (int nt = 0; nt < 4; ++nt)
        bp[nt] = *(const bf16x8*)(W2f + ((size_t)((h * 4 + nt) * 64 + lane)) * 8);

    bf16x8 a[8];
#pragma unroll
    for (int kt = 0; kt < 4; ++kt) {
        bf16x8 fa;
#pragma unroll
        for (int i = 0; i < 4; ++i) { fa[i] = (__bf16)r0[kt][i]; fa[4 + i] = (__bf16)r1[kt][i]; }
        a[kt] = fa;
        a[4 + kt] = ag[kt];
    }

    f32x4 acc[4] = {};
#pragma unroll
    for (int kt = 0; kt < 8; ++kt) {
        if (kt + 1 < 8) {
#pragma unroll
            for (int nt = 0; nt < 4; ++nt) {
                bf16x8 v = *(const bf16x8*)(W2f + ((size_t)(((kt + 1) * 8 + h * 4 + nt) * 64 + lane)) * 8);
                if (kt & 1) bp[nt] = v; else bq[nt] = v;
            }
        }
#pragma unroll
        for (int nt = 0; nt < 4; ++nt) {
            bf16x8 cur = (kt & 1) ? bq[nt] : bp[nt];
            acc[nt] = __builtin_amdgcn_mfma_f32_16x16x32_bf16(a[kt], cur, acc[nt], 0, 0, 0);
        }
    }

    float bias[4];
#pragma unroll
    for (int nt = 0; nt < 4; ++nt) bias[nt] = b2f[(h * 4 + nt) * 16 + c];

#pragma unroll
    for (int r = 0; r < 4; ++r) {
        int row = tile * 16 + kh * 4 + r;
#pragma unroll
        for (int nt = 0; nt < 4; ++nt)
            __builtin_nontemporal_store(gelu_fast(acc[nt][r] + bias[nt]),
                                        &out[(size_t)row * DD + (h * 4 + nt) * 16 + c]);
    }
}

extern "C" void kernel_launch(void* const* d_in, const int* in_sizes, int n_in,
                              void* d_out, int out_size, void* d_ws, size_t ws_size,
                              hipStream_t stream) {
    const float* node_repr = (const float*)d_in[0];
    const int*   edges     = (const int*)d_in[1];
    const float* g1 = (const float*)d_in[2];
    const float* be1 = (const float*)d_in[3];
    const float* m1 = (const float*)d_in[4];
    const float* v1 = (const float*)d_in[5];
    const float* W1 = (const float*)d_in[6];
    const float* b1 = (const float*)d_in[7];
    const float* g2 = (const float*)d_in[8];
    const float* be2 = (const float*)d_in[9];
    const float* m2 = (const float*)d_in[10];
    const float* v2 = (const float*)d_in[11];
    const float* W2 = (const float*)d_in[12];
    const float* b2 = (const float*)d_in[13];

    char* ws = (char*)d_ws;
    __bf16* W1f = (__bf16*)(ws + W1F_OFF);
    __bf16* W2f = (__bf16*)(ws + W2F_OFF);
    float* b1f = (float*)(ws + B1F_OFF);
    float* b2f = (float*)(ws + B2F_OFF);
    __bf16* T  = (__bf16*)(ws + T_OFF);
    int* deg   = (int*)(ws + DEG_OFF);
    int* offs  = (int*)(ws + OFFS_OFF);
    int* elist = (int*)(ws + ELIST_OFF);
    int* cntg  = (int*)(ws + CNTG_OFF);
    int* bofs  = (int*)(ws + BOFS_OFF);
    int* bsum  = (int*)(ws + BSUM_OFF);
    int* boff  = (int*)(ws + BOFF_OFF);
    __bf16* Agg = (__bf16*)(ws + AGG_OFF);
    int* pairbuf = (int*)(ws + AGG_OFF);
    float* out = (float*)d_out;

    hipMemsetAsync(deg, 0, (size_t)NN * 4, stream);

    hipLaunchKernelGGL(prep_kernel, dim3(2756 + NBLK), dim3(256), 0, stream,
                       g1, be1, m1, v1, W1, b1, g2, be2, m2, v2, W2, b2,
                       edges, W1f, W2f, b1f, b2f, deg, cntg);

    hipLaunchKernelGGL(sortb_kernel, dim3(NBLK), dim3(256), 0, stream, cntg, bofs, bsum);
    hipLaunchKernelGGL(scan_top_kernel, dim3(1), dim3(512), 0, stream, bsum, boff);

    hipLaunchKernelGGL(sortc_kernel, dim3(NBLK), dim3(256), 0, stream,
                       edges, boff, bofs, pairbuf);
    hipLaunchKernelGGL(p2_kernel, dim3(NBLK), dim3(256), 0, stream,
                       deg, boff, pairbuf, elist, offs);

    hipLaunchKernelGGL(ffn1_kernel, dim3((NTILE + 7) / 8), dim3(256), 0, stream,
                       node_repr, W1f, b1f, T);

    hipLaunchKernelGGL(agg_kernel, dim3((NN * 16 + 255) / 256), dim3(256), 0, stream,
                       T, offs, deg, elist, Agg);

    hipLaunchKernelGGL(ffn2_kernel, dim3((NTILE * 2 + 3) / 4), dim3(256), 0, stream,
                       node_repr, Agg, W2f, b2f, out);
}

// Round 14
// 110.677 us; speedup vs baseline: 1.3231x; 1.2840x over previous
//
#include <hip/hip_runtime.h>

#define NN 100000
#define DD 128
#define EE 640000
#define BN_EPS 1e-3f
#define NBLK 391    // ceil(NN/256); #buckets and #sort blocks
#define NTILE 6250  // NN/16 exactly
#define EPB 1637    // edges per sort block: 391*1637 >= EE

typedef __bf16 bf16x8 __attribute__((ext_vector_type(8)));
typedef float f32x4 __attribute__((ext_vector_type(4)));

// ---- workspace byte offsets ----
#define W1F_OFF 0u
#define W2F_OFF 32768u
#define B1F_OFF 98304u
#define B2F_OFF 98816u
#define T_OFF   99328u
#define OFFS_OFF 26099328u    // NN+1 ints (region has 200000-int slack)
#define ELIST_OFF 26899328u   // EE int; head aliases cntg+bofs (dead before p2)
#define CNTG_OFF ELIST_OFF               // 391*391 int
#define BOFS_OFF (ELIST_OFF + 611524u)   // 391*391 int
#define BSUM_OFF 29459328u
#define BOFF_OFF 29461376u
#define AGG_OFF 29464576u     // NN*128 bf16; aliases pairbuf (EE int) before agg runs

// tanh-form gelu; max |err| vs exact ~3e-4 (threshold 9.8e-2)
__device__ __forceinline__ float gelu_fast(float x) {
    float x3 = x * x * x;
    float z2 = 1.5957691216057308f * x + 0.07135481627002407f * x3;
    return x / (1.0f + __expf(-z2));
}

// prep: [0,64) fold_bias | [64,256) fold_w | [256,647) sortA per-slice bucket counts
__global__ __launch_bounds__(256) void prep_kernel(
    const float* __restrict__ g1, const float* __restrict__ be1,
    const float* __restrict__ m1, const float* __restrict__ v1,
    const float* __restrict__ W1, const float* __restrict__ b1,
    const float* __restrict__ g2, const float* __restrict__ be2,
    const float* __restrict__ m2, const float* __restrict__ v2,
    const float* __restrict__ W2, const float* __restrict__ b2,
    const int* __restrict__ edges,
    __bf16* __restrict__ W1f, __bf16* __restrict__ W2f,
    float* __restrict__ b1f, float* __restrict__ b2f,
    int* __restrict__ cntg)
{
    const int blk = blockIdx.x;
    const int t = threadIdx.x;
    if (blk < 64) {
        const int w = (blk * 256 + t) >> 6;
        const int lane = t & 63;
        if (w < 128) {
            float acc = 0.f;
            for (int k = lane; k < 128; k += 64) {
                float s = g1[k] * rsqrtf(v1[k] + BN_EPS);
                float sh = be1[k] - m1[k] * s;
                acc += sh * W1[k * 128 + w];
            }
#pragma unroll
            for (int off = 32; off > 0; off >>= 1) acc += __shfl_down(acc, off);
            if (lane == 0) b1f[w] = acc + b1[w];
        } else {
            const int n = w - 128;
            float acc = 0.f;
            for (int k = lane; k < 256; k += 64) {
                float s = g2[k] * rsqrtf(v2[k] + BN_EPS);
                float sh = be2[k] - m2[k] * s;
                acc += sh * W2[k * 128 + n];
            }
#pragma unroll
            for (int off = 32; off > 0; off >>= 1) acc += __shfl_down(acc, off);
            if (lane == 0) b2f[n] = acc + b2[n];
        }
    } else if (blk < 256) {
        int tid = (blk - 64) * 256 + t;
        if (tid < 16384) {
            int idx = tid;
            int i = idx & 7, l = (idx >> 3) & 63, nt = (idx >> 9) & 7, kt = idx >> 12;
            int k = kt * 32 + (l >> 4) * 8 + i;
            int n = nt * 16 + (l & 15);
            float s = g1[k] * rsqrtf(v1[k] + BN_EPS);
            W1f[idx] = (__bf16)(s * W1[k * 128 + n]);
        } else {
            int idx = tid - 16384;
            int i = idx & 7, l = (idx >> 3) & 63, nt = (idx >> 9) & 7, kt = idx >> 12;
            int n = nt * 16 + (l & 15);
            int row;
            if (kt < 4) {
                row = kt * 32 + (l >> 4) * 8 + i;
            } else {
                int q = (kt - 4) * 32 + (l >> 4) * 8 + i;
                row = 128 + ((q & 7) * 16 + (q >> 3));
            }
            float s = g2[row] * rsqrtf(v2[row] + BN_EPS);
            W2f[idx] = (__bf16)(s * W2[row * 128 + n]);
        }
    } else {
        __shared__ int cnt[NBLK];
        const int k = blk - 256;
        for (int b = t; b < NBLK; b += 256) cnt[b] = 0;
        __syncthreads();
        const int e0 = k * EPB, e1 = min(e0 + EPB, EE);
        for (int e = e0 + t; e < e1; e += 256)
            atomicAdd(&cnt[edges[e] >> 8], 1);
        __syncthreads();
        for (int b = t; b < NBLK; b += 256) cntg[k * NBLK + b] = cnt[b];
    }
}

// sortB: bucket b; exclusive scan of cntg[k][b] over k -> bofs; total -> bsum[b]
__global__ __launch_bounds__(256) void sortb_kernel(const int* __restrict__ cntg,
                                                    int* __restrict__ bofs,
                                                    int* __restrict__ bsum)
{
    const int b = blockIdx.x, t = threadIdx.x;
    __shared__ int sp[256];
    int ia = 2 * t, ib = 2 * t + 1;
    int va = (ia < NBLK) ? cntg[ia * NBLK + b] : 0;
    int vb = (ib < NBLK) ? cntg[ib * NBLK + b] : 0;
    sp[t] = va + vb;
    __syncthreads();
    for (int off = 1; off < 256; off <<= 1) {
        int tmp = (t >= off) ? sp[t - off] : 0;
        __syncthreads();
        sp[t] += tmp;
        __syncthreads();
    }
    int pexcl = sp[t] - (va + vb);
    if (ia < NBLK) bofs[b * NBLK + ia] = pexcl;
    if (ib < NBLK) bofs[b * NBLK + ib] = pexcl + va;
    if (t == 255) bsum[b] = sp[255];
}

// single-block exclusive scan of NBLK bucket totals -> boff (bucket bases)
__global__ __launch_bounds__(512) void scan_top_kernel(const int* __restrict__ bsum,
                                                       int* __restrict__ boff)
{
    __shared__ int s[512];
    const int t = threadIdx.x;
    int v = (t < NBLK) ? bsum[t] : 0;
    s[t] = v;
    __syncthreads();
    for (int off = 1; off < 512; off <<= 1) {
        int tmp = (t >= off) ? s[t - off] : 0;
        __syncthreads();
        s[t] += tmp;
        __syncthreads();
    }
    if (t < NBLK) boff[t] = s[t] - v;
}

// fused: [0,NBLK) sortC (scatter edges into bucket-sorted pairbuf, LDS cursors
// precomputed -> no global atomics) | [NBLK, NBLK+782) ffn1 (W1f in 32 KB LDS,
// 8 consecutive tiles/block). Independent inputs -> co-scheduled.
__global__ __launch_bounds__(256) void sortc_ffn1_kernel(
    const int* __restrict__ edges, const int* __restrict__ boff,
    const int* __restrict__ bofs, int* __restrict__ pairbuf,
    const float* __restrict__ X, const __bf16* __restrict__ W1f,
    const float* __restrict__ b1f, __bf16* __restrict__ T)
{
    __shared__ __bf16 sW[16384];   // ffn1: weight stage; sortC: aliased as cursors
    const int t = threadIdx.x;
    if (blockIdx.x < NBLK) {
        int* cur = (int*)sW;
        const int k = blockIdx.x;
        for (int b = t; b < NBLK; b += 256)
            cur[b] = boff[b] + bofs[b * NBLK + k];
        __syncthreads();
        const int e0 = k * EPB, e1 = min(e0 + EPB, EE);
        for (int e = e0 + t; e < e1; e += 256) {
            int dst = edges[e];
            int src = edges[EE + e];
            int pos = atomicAdd(&cur[dst >> 8], 1);
            pairbuf[pos] = (src << 8) | (dst & 255);
        }
        return;
    }
#pragma unroll
    for (int i = 0; i < 8; ++i) {
        int ch = i * 256 + t;
        *(bf16x8*)(sW + ch * 8) = *(const bf16x8*)(W1f + (size_t)ch * 8);
    }
    __syncthreads();

    const int wave = t >> 6;
    const int lane = t & 63;
    const int c = lane & 15, kh = lane >> 4;
    const int tbase = (blockIdx.x - NBLK) * 8;

    float bias[8];
#pragma unroll
    for (int nt = 0; nt < 8; ++nt) bias[nt] = b1f[nt * 16 + c];

#pragma unroll
    for (int s = 0; s < 2; ++s) {
        const int tile = tbase + s * 4 + wave;
        if (tile >= NTILE) break;
        const float* xr = X + (size_t)(tile * 16 + c) * DD + kh * 8;
        f32x4 r0[4], r1[4];
#pragma unroll
        for (int q = 0; q < 4; ++q) {
            r0[q] = *(const f32x4*)(xr + q * 32);
            r1[q] = *(const f32x4*)(xr + q * 32 + 4);
        }
        bf16x8 af[4];
#pragma unroll
        for (int kt = 0; kt < 4; ++kt) {
            bf16x8 fa;
#pragma unroll
            for (int i = 0; i < 4; ++i) { fa[i] = (__bf16)r0[kt][i]; fa[4 + i] = (__bf16)r1[kt][i]; }
            af[kt] = fa;
        }
        f32x4 acc[8] = {};
#pragma unroll
        for (int kt = 0; kt < 4; ++kt)
#pragma unroll
            for (int nt = 0; nt < 8; ++nt) {
                bf16x8 bfr = *(const bf16x8*)(sW + ((kt * 8 + nt) * 64 + lane) * 8);
                acc[nt] = __builtin_amdgcn_mfma_f32_16x16x32_bf16(af[kt], bfr, acc[nt], 0, 0, 0);
            }
#pragma unroll
        for (int r = 0; r < 4; ++r) {
            int row = tile * 16 + kh * 4 + r;
            bf16x8 o;
#pragma unroll
            for (int nt = 0; nt < 8; ++nt)
                o[nt] = (__bf16)gelu_fast(acc[nt][r] + bias[nt]);
            *(bf16x8*)(T + (size_t)row * DD + c * 8) = o;
        }
    }
}

// p2: per bucket — LDS histogram of the bucket's pairbuf segment gives per-node
// counts (no global deg/hist needed); scan -> offs (+ sentinel offs[NN]=EE),
// seed cursors, scatter into per-node elist segments.
__global__ __launch_bounds__(256) void p2_kernel(const int* __restrict__ boff,
                                                 const int* __restrict__ pairbuf,
                                                 int* __restrict__ elist,
                                                 int* __restrict__ offs)
{
    __shared__ int s[256];
    __shared__ int cur[256];
    const int b = blockIdx.x, t = threadIdx.x;
    const int start = boff[b];
    const int end = (b + 1 < NBLK) ? boff[b + 1] : EE;
    cur[t] = 0;
    __syncthreads();
    for (int e = start + t; e < end; e += 256)
        atomicAdd(&cur[pairbuf[e] & 255], 1);
    __syncthreads();
    int v = cur[t];
    s[t] = v;
    __syncthreads();
    for (int off = 1; off < 256; off <<= 1) {
        int tmp = (t >= off) ? s[t - off] : 0;
        __syncthreads();
        s[t] += tmp;
        __syncthreads();
    }
    int ex = s[t] - v + start;
    const int node = b * 256 + t;
    if (node <= NN) offs[node] = ex;   // node==NN (b=390,t=160) -> sentinel EE
    __syncthreads();
    cur[t] = ex;
    __syncthreads();
    for (int e = start + t; e < end; e += 256) {
        int item = pairbuf[e];
        int pos = atomicAdd(&cur[item & 255], 1);
        elist[pos] = item >> 8;
    }
}

// gather-mean: 16 threads/node; coalesced elist load + __shfl broadcast;
// d = offs[n+1]-offs[n].
__global__ __launch_bounds__(256) void agg_kernel(
    const __bf16* __restrict__ T, const int* __restrict__ offs,
    const int* __restrict__ elist, __bf16* __restrict__ Agg)
{
    int t = blockIdx.x * 256 + threadIdx.x;
    int node = t >> 4, j = t & 15;
    if (node >= NN) return;
    const int lane = threadIdx.x & 63;
    const int gbase = lane & 48;
    const int beg = offs[node];
    const int end = offs[node + 1];
    const int d = end - beg;
    float acc[8] = {};
    for (int eb = beg; eb < end; eb += 16) {
        int me = eb + (lane & 15);
        int sv = (me < end) ? elist[me] : 0;
        int cnt = min(end - eb, 16);
        int i = 0;
        for (; i + 3 < cnt; i += 4) {
            int s0 = __shfl(sv, gbase + i);
            int s1 = __shfl(sv, gbase + i + 1);
            int s2 = __shfl(sv, gbase + i + 2);
            int s3 = __shfl(sv, gbase + i + 3);
            bf16x8 v0 = *(const bf16x8*)(T + (size_t)s0 * DD + j * 8);
            bf16x8 v1 = *(const bf16x8*)(T + (size_t)s1 * DD + j * 8);
            bf16x8 v2 = *(const bf16x8*)(T + (size_t)s2 * DD + j * 8);
            bf16x8 v3 = *(const bf16x8*)(T + (size_t)s3 * DD + j * 8);
#pragma unroll
            for (int q = 0; q < 8; ++q)
                acc[q] += ((float)v0[q] + (float)v1[q]) + ((float)v2[q] + (float)v3[q]);
        }
        for (; i < cnt; ++i) {
            int s0 = __shfl(sv, gbase + i);
            bf16x8 v0 = *(const bf16x8*)(T + (size_t)s0 * DD + j * 8);
#pragma unroll
            for (int q = 0; q < 8; ++q) acc[q] += (float)v0[q];
        }
    }
    const float inv = 1.0f / fmaxf((float)d, 1.0f);
    bf16x8 o;
#pragma unroll
    for (int q = 0; q < 8; ++q) o[q] = (__bf16)(acc[q] * inv);
    *(bf16x8*)(Agg + (size_t)node * DD + j * 8) = o;
}

// out = gelu([X, Agg] @ W2f + b2f); unit = tile*2+half, both halves of a tile
// in the SAME block (X/Agg L1 reuse); reg ping-pong B prefetch; PLAIN stores
// (NT stores measured +12 MB write amplification).
__global__ __launch_bounds__(256) void ffn2_kernel(
    const float* __restrict__ X, const __bf16* __restrict__ Agg,
    const __bf16* __restrict__ W2f, const float* __restrict__ b2f,
    float* __restrict__ out)
{
    const int wave = threadIdx.x >> 6;
    const int lane = threadIdx.x & 63;
    const int unit = blockIdx.x * 4 + wave;   // = tile*2 + half
    const int tile = unit >> 1;
    const int h = unit & 1;
    if (tile >= NTILE) return;
    const int c = lane & 15, kh = lane >> 4;

    const int rowA = tile * 16 + c;
    const float* xr = X + (size_t)rowA * DD + kh * 8;
    const __bf16* ar = Agg + (size_t)rowA * DD + kh * 8;

    f32x4 r0[4], r1[4];
    bf16x8 ag[4];
#pragma unroll
    for (int q = 0; q < 4; ++q) {
        r0[q] = *(const f32x4*)(xr + q * 32);
        r1[q] = *(const f32x4*)(xr + q * 32 + 4);
        ag[q] = *(const bf16x8*)(ar + q * 32);
    }
    bf16x8 bp[4], bq[4];
#pragma unroll
    for (int nt = 0; nt < 4; ++nt)
        bp[nt] = *(const bf16x8*)(W2f + ((size_t)((h * 4 + nt) * 64 + lane)) * 8);

    bf16x8 a[8];
#pragma unroll
    for (int kt = 0; kt < 4; ++kt) {
        bf16x8 fa;
#pragma unroll
        for (int i = 0; i < 4; ++i) { fa[i] = (__bf16)r0[kt][i]; fa[4 + i] = (__bf16)r1[kt][i]; }
        a[kt] = fa;
        a[4 + kt] = ag[kt];
    }

    f32x4 acc[4] = {};
#pragma unroll
    for (int kt = 0; kt < 8; ++kt) {
        if (kt + 1 < 8) {
#pragma unroll
            for (int nt = 0; nt < 4; ++nt) {
                bf16x8 v = *(const bf16x8*)(W2f + ((size_t)(((kt + 1) * 8 + h * 4 + nt) * 64 + lane)) * 8);
                if (kt & 1) bp[nt] = v; else bq[nt] = v;
            }
        }
#pragma unroll
        for (int nt = 0; nt < 4; ++nt) {
            bf16x8 cur = (kt & 1) ? bq[nt] : bp[nt];
            acc[nt] = __builtin_amdgcn_mfma_f32_16x16x32_bf16(a[kt], cur, acc[nt], 0, 0, 0);
        }
    }

    float bias[4];
#pragma unroll
    for (int nt = 0; nt < 4; ++nt) bias[nt] = b2f[(h * 4 + nt) * 16 + c];

#pragma unroll
    for (int r = 0; r < 4; ++r) {
        int row = tile * 16 + kh * 4 + r;
#pragma unroll
        for (int nt = 0; nt < 4; ++nt)
            out[(size_t)row * DD + (h * 4 + nt) * 16 + c] = gelu_fast(acc[nt][r] + bias[nt]);
    }
}

extern "C" void kernel_launch(void* const* d_in, const int* in_sizes, int n_in,
                              void* d_out, int out_size, void* d_ws, size_t ws_size,
                              hipStream_t stream) {
    const float* node_repr = (const float*)d_in[0];
    const int*   edges     = (const int*)d_in[1];
    const float* g1 = (const float*)d_in[2];
    const float* be1 = (const float*)d_in[3];
    const float* m1 = (const float*)d_in[4];
    const float* v1 = (const float*)d_in[5];
    const float* W1 = (const float*)d_in[6];
    const float* b1 = (const float*)d_in[7];
    const float* g2 = (const float*)d_in[8];
    const float* be2 = (const float*)d_in[9];
    const float* m2 = (const float*)d_in[10];
    const float* v2 = (const float*)d_in[11];
    const float* W2 = (const float*)d_in[12];
    const float* b2 = (const float*)d_in[13];

    char* ws = (char*)d_ws;
    __bf16* W1f = (__bf16*)(ws + W1F_OFF);
    __bf16* W2f = (__bf16*)(ws + W2F_OFF);
    float* b1f = (float*)(ws + B1F_OFF);
    float* b2f = (float*)(ws + B2F_OFF);
    __bf16* T  = (__bf16*)(ws + T_OFF);
    int* offs  = (int*)(ws + OFFS_OFF);
    int* elist = (int*)(ws + ELIST_OFF);
    int* cntg  = (int*)(ws + CNTG_OFF);
    int* bofs  = (int*)(ws + BOFS_OFF);
    int* bsum  = (int*)(ws + BSUM_OFF);
    int* boff  = (int*)(ws + BOFF_OFF);
    __bf16* Agg = (__bf16*)(ws + AGG_OFF);
    int* pairbuf = (int*)(ws + AGG_OFF);
    float* out = (float*)d_out;

    hipLaunchKernelGGL(prep_kernel, dim3(256 + NBLK), dim3(256), 0, stream,
                       g1, be1, m1, v1, W1, b1, g2, be2, m2, v2, W2, b2,
                       edges, W1f, W2f, b1f, b2f, cntg);

    hipLaunchKernelGGL(sortb_kernel, dim3(NBLK), dim3(256), 0, stream, cntg, bofs, bsum);
    hipLaunchKernelGGL(scan_top_kernel, dim3(1), dim3(512), 0, stream, bsum, boff);

    hipLaunchKernelGGL(sortc_ffn1_kernel, dim3(NBLK + (NTILE + 7) / 8), dim3(256), 0, stream,
                       edges, boff, bofs, pairbuf, node_repr, W1f, b1f, T);

    hipLaunchKernelGGL(p2_kernel, dim3(NBLK), dim3(256), 0, stream,
                       boff, pairbuf, elist, offs);

    hipLaunchKernelGGL(agg_kernel, dim3((NN * 16 + 255) / 256), dim3(256), 0, stream,
                       T, offs, elist, Agg);

    hipLaunchKernelGGL(ffn2_kernel, dim3((NTILE * 2 + 3) / 4), dim3(256), 0, stream,
                       node_repr, Agg, W2f, b2f, out);
}

// Round 15
// 106.742 us; speedup vs baseline: 1.3719x; 1.0369x over previous
//
#include <hip/hip_runtime.h>

#define NN 100000
#define DD 128
#define EE 640000
#define BN_EPS 1e-3f
#define NBLK 391    // ceil(NN/256); #buckets and #sort blocks
#define NTILE 6250  // NN/16 exactly
#define EPB 1637    // edges per sort block: 391*1637 >= EE
#define FFN2_BLKS 768

typedef __bf16 bf16x8 __attribute__((ext_vector_type(8)));
typedef float f32x4 __attribute__((ext_vector_type(4)));

// ---- workspace byte offsets (ws_size ~268 MB, verified via poison fill) ----
#define W1F_OFF 0u
#define W2F_OFF 32768u
#define B1F_OFF 98304u
#define B2F_OFF 98816u
#define T_OFF   99328u
#define OFFS_OFF 26099328u    // NN+1 ints
#define ELIST_OFF 26899328u   // EE int; head aliases cntg+bofs (dead before p2)
#define CNTG_OFF ELIST_OFF               // 391*391 int
#define BOFS_OFF (ELIST_OFF + 611524u)   // 391*391 int
#define BSUM_OFF 29459328u
#define BOFF_OFF 29461376u
#define AGG_OFF 29464576u     // NN*128 bf16; aliases pairbuf (EE int) before agg runs
#define XB_OFF  55064576u     // NN*128 bf16 (X in bf16, logical layout)

// tanh-form gelu; max |err| vs exact ~3e-4 (threshold 9.8e-2)
__device__ __forceinline__ float gelu_fast(float x) {
    float x3 = x * x * x;
    float z2 = 1.5957691216057308f * x + 0.07135481627002407f * x3;
    return x / (1.0f + __expf(-z2));
}

// prep: [0,64) fold_bias | [64,256) fold_w | [256,647) sortA per-slice bucket counts
__global__ __launch_bounds__(256) void prep_kernel(
    const float* __restrict__ g1, const float* __restrict__ be1,
    const float* __restrict__ m1, const float* __restrict__ v1,
    const float* __restrict__ W1, const float* __restrict__ b1,
    const float* __restrict__ g2, const float* __restrict__ be2,
    const float* __restrict__ m2, const float* __restrict__ v2,
    const float* __restrict__ W2, const float* __restrict__ b2,
    const int* __restrict__ edges,
    __bf16* __restrict__ W1f, __bf16* __restrict__ W2f,
    float* __restrict__ b1f, float* __restrict__ b2f,
    int* __restrict__ cntg)
{
    const int blk = blockIdx.x;
    const int t = threadIdx.x;
    if (blk < 64) {
        const int w = (blk * 256 + t) >> 6;
        const int lane = t & 63;
        if (w < 128) {
            float acc = 0.f;
            for (int k = lane; k < 128; k += 64) {
                float s = g1[k] * rsqrtf(v1[k] + BN_EPS);
                float sh = be1[k] - m1[k] * s;
                acc += sh * W1[k * 128 + w];
            }
#pragma unroll
            for (int off = 32; off > 0; off >>= 1) acc += __shfl_down(acc, off);
            if (lane == 0) b1f[w] = acc + b1[w];
        } else {
            const int n = w - 128;
            float acc = 0.f;
            for (int k = lane; k < 256; k += 64) {
                float s = g2[k] * rsqrtf(v2[k] + BN_EPS);
                float sh = be2[k] - m2[k] * s;
                acc += sh * W2[k * 128 + n];
            }
#pragma unroll
            for (int off = 32; off > 0; off >>= 1) acc += __shfl_down(acc, off);
            if (lane == 0) b2f[n] = acc + b2[n];
        }
    } else if (blk < 256) {
        int tid = (blk - 64) * 256 + t;
        if (tid < 16384) {
            int idx = tid;
            int i = idx & 7, l = (idx >> 3) & 63, nt = (idx >> 9) & 7, kt = idx >> 12;
            int k = kt * 32 + (l >> 4) * 8 + i;
            int n = nt * 16 + (l & 15);
            float s = g1[k] * rsqrtf(v1[k] + BN_EPS);
            W1f[idx] = (__bf16)(s * W1[k * 128 + n]);
        } else {
            int idx = tid - 16384;
            int i = idx & 7, l = (idx >> 3) & 63, nt = (idx >> 9) & 7, kt = idx >> 12;
            int n = nt * 16 + (l & 15);
            int row;
            if (kt < 4) {
                row = kt * 32 + (l >> 4) * 8 + i;
            } else {
                int q = (kt - 4) * 32 + (l >> 4) * 8 + i;
                row = 128 + ((q & 7) * 16 + (q >> 3));
            }
            float s = g2[row] * rsqrtf(v2[row] + BN_EPS);
            W2f[idx] = (__bf16)(s * W2[row * 128 + n]);
        }
    } else {
        __shared__ int cnt[NBLK];
        const int k = blk - 256;
        for (int b = t; b < NBLK; b += 256) cnt[b] = 0;
        __syncthreads();
        const int e0 = k * EPB, e1 = min(e0 + EPB, EE);
        for (int e = e0 + t; e < e1; e += 256)
            atomicAdd(&cnt[edges[e] >> 8], 1);
        __syncthreads();
        for (int b = t; b < NBLK; b += 256) cntg[k * NBLK + b] = cnt[b];
    }
}

// sortB: bucket b; exclusive scan of cntg[k][b] over k -> bofs; total -> bsum[b]
__global__ __launch_bounds__(256) void sortb_kernel(const int* __restrict__ cntg,
                                                    int* __restrict__ bofs,
                                                    int* __restrict__ bsum)
{
    const int b = blockIdx.x, t = threadIdx.x;
    __shared__ int sp[256];
    int ia = 2 * t, ib = 2 * t + 1;
    int va = (ia < NBLK) ? cntg[ia * NBLK + b] : 0;
    int vb = (ib < NBLK) ? cntg[ib * NBLK + b] : 0;
    sp[t] = va + vb;
    __syncthreads();
    for (int off = 1; off < 256; off <<= 1) {
        int tmp = (t >= off) ? sp[t - off] : 0;
        __syncthreads();
        sp[t] += tmp;
        __syncthreads();
    }
    int pexcl = sp[t] - (va + vb);
    if (ia < NBLK) bofs[b * NBLK + ia] = pexcl;
    if (ib < NBLK) bofs[b * NBLK + ib] = pexcl + va;
    if (t == 255) bsum[b] = sp[255];
}

// single-block exclusive scan of NBLK bucket totals -> boff (bucket bases)
__global__ __launch_bounds__(512) void scan_top_kernel(const int* __restrict__ bsum,
                                                       int* __restrict__ boff)
{
    __shared__ int s[512];
    const int t = threadIdx.x;
    int v = (t < NBLK) ? bsum[t] : 0;
    s[t] = v;
    __syncthreads();
    for (int off = 1; off < 512; off <<= 1) {
        int tmp = (t >= off) ? s[t - off] : 0;
        __syncthreads();
        s[t] += tmp;
        __syncthreads();
    }
    if (t < NBLK) boff[t] = s[t] - v;
}

// fused: [0,NBLK) sortC | [NBLK,...) ffn1 (W1f in 32 KB LDS, 8 tiles/block).
// ffn1 additionally emits Xb = bf16(X) in logical layout for ffn2.
__global__ __launch_bounds__(256) void sortc_ffn1_kernel(
    const int* __restrict__ edges, const int* __restrict__ boff,
    const int* __restrict__ bofs, int* __restrict__ pairbuf,
    const float* __restrict__ X, const __bf16* __restrict__ W1f,
    const float* __restrict__ b1f, __bf16* __restrict__ T,
    __bf16* __restrict__ Xb)
{
    __shared__ __bf16 sW[16384];   // ffn1: weight stage; sortC: aliased as cursors
    const int t = threadIdx.x;
    if (blockIdx.x < NBLK) {
        int* cur = (int*)sW;
        const int k = blockIdx.x;
        for (int b = t; b < NBLK; b += 256)
            cur[b] = boff[b] + bofs[b * NBLK + k];
        __syncthreads();
        const int e0 = k * EPB, e1 = min(e0 + EPB, EE);
        for (int e = e0 + t; e < e1; e += 256) {
            int dst = edges[e];
            int src = edges[EE + e];
            int pos = atomicAdd(&cur[dst >> 8], 1);
            pairbuf[pos] = (src << 8) | (dst & 255);
        }
        return;
    }
#pragma unroll
    for (int i = 0; i < 8; ++i) {
        int ch = i * 256 + t;
        *(bf16x8*)(sW + ch * 8) = *(const bf16x8*)(W1f + (size_t)ch * 8);
    }
    __syncthreads();

    const int wave = t >> 6;
    const int lane = t & 63;
    const int c = lane & 15, kh = lane >> 4;
    const int tbase = (blockIdx.x - NBLK) * 8;

    float bias[8];
#pragma unroll
    for (int nt = 0; nt < 8; ++nt) bias[nt] = b1f[nt * 16 + c];

#pragma unroll
    for (int s = 0; s < 2; ++s) {
        const int tile = tbase + s * 4 + wave;
        if (tile >= NTILE) break;
        const size_t rowb = (size_t)(tile * 16 + c) * DD;
        const float* xr = X + rowb + kh * 8;
        f32x4 r0[4], r1[4];
#pragma unroll
        for (int q = 0; q < 4; ++q) {
            r0[q] = *(const f32x4*)(xr + q * 32);
            r1[q] = *(const f32x4*)(xr + q * 32 + 4);
        }
        bf16x8 af[4];
#pragma unroll
        for (int kt = 0; kt < 4; ++kt) {
            bf16x8 fa;
#pragma unroll
            for (int i = 0; i < 4; ++i) { fa[i] = (__bf16)r0[kt][i]; fa[4 + i] = (__bf16)r1[kt][i]; }
            af[kt] = fa;
        }
        // emit bf16 X (logical layout) for ffn2
#pragma unroll
        for (int kt = 0; kt < 4; ++kt)
            *(bf16x8*)(Xb + rowb + kt * 32 + kh * 8) = af[kt];

        f32x4 acc[8] = {};
#pragma unroll
        for (int kt = 0; kt < 4; ++kt)
#pragma unroll
            for (int nt = 0; nt < 8; ++nt) {
                bf16x8 bfr = *(const bf16x8*)(sW + ((kt * 8 + nt) * 64 + lane) * 8);
                acc[nt] = __builtin_amdgcn_mfma_f32_16x16x32_bf16(af[kt], bfr, acc[nt], 0, 0, 0);
            }
#pragma unroll
        for (int r = 0; r < 4; ++r) {
            int row = tile * 16 + kh * 4 + r;
            bf16x8 o;
#pragma unroll
            for (int nt = 0; nt < 8; ++nt)
                o[nt] = (__bf16)gelu_fast(acc[nt][r] + bias[nt]);
            *(bf16x8*)(T + (size_t)row * DD + c * 8) = o;
        }
    }
}

// p2: per bucket — LDS histogram -> offs (+ sentinel), seed cursors, scatter elist
__global__ __launch_bounds__(256) void p2_kernel(const int* __restrict__ boff,
                                                 const int* __restrict__ pairbuf,
                                                 int* __restrict__ elist,
                                                 int* __restrict__ offs)
{
    __shared__ int s[256];
    __shared__ int cur[256];
    const int b = blockIdx.x, t = threadIdx.x;
    const int start = boff[b];
    const int end = (b + 1 < NBLK) ? boff[b + 1] : EE;
    cur[t] = 0;
    __syncthreads();
    for (int e = start + t; e < end; e += 256)
        atomicAdd(&cur[pairbuf[e] & 255], 1);
    __syncthreads();
    int v = cur[t];
    s[t] = v;
    __syncthreads();
    for (int off = 1; off < 256; off <<= 1) {
        int tmp = (t >= off) ? s[t - off] : 0;
        __syncthreads();
        s[t] += tmp;
        __syncthreads();
    }
    int ex = s[t] - v + start;
    const int node = b * 256 + t;
    if (node <= NN) offs[node] = ex;
    __syncthreads();
    cur[t] = ex;
    __syncthreads();
    for (int e = start + t; e < end; e += 256) {
        int item = pairbuf[e];
        int pos = atomicAdd(&cur[item & 255], 1);
        elist[pos] = item >> 8;
    }
}

// gather-mean: 16 threads/node; coalesced elist load + __shfl broadcast
__global__ __launch_bounds__(256) void agg_kernel(
    const __bf16* __restrict__ T, const int* __restrict__ offs,
    const int* __restrict__ elist, __bf16* __restrict__ Agg)
{
    int t = blockIdx.x * 256 + threadIdx.x;
    int node = t >> 4, j = t & 15;
    if (node >= NN) return;
    const int lane = threadIdx.x & 63;
    const int gbase = lane & 48;
    const int beg = offs[node];
    const int end = offs[node + 1];
    const int d = end - beg;
    float acc[8] = {};
    for (int eb = beg; eb < end; eb += 16) {
        int me = eb + (lane & 15);
        int sv = (me < end) ? elist[me] : 0;
        int cnt = min(end - eb, 16);
        int i = 0;
        for (; i + 3 < cnt; i += 4) {
            int s0 = __shfl(sv, gbase + i);
            int s1 = __shfl(sv, gbase + i + 1);
            int s2 = __shfl(sv, gbase + i + 2);
            int s3 = __shfl(sv, gbase + i + 3);
            bf16x8 v0 = *(const bf16x8*)(T + (size_t)s0 * DD + j * 8);
            bf16x8 v1 = *(const bf16x8*)(T + (size_t)s1 * DD + j * 8);
            bf16x8 v2 = *(const bf16x8*)(T + (size_t)s2 * DD + j * 8);
            bf16x8 v3 = *(const bf16x8*)(T + (size_t)s3 * DD + j * 8);
#pragma unroll
            for (int q = 0; q < 8; ++q)
                acc[q] += ((float)v0[q] + (float)v1[q]) + ((float)v2[q] + (float)v3[q]);
        }
        for (; i < cnt; ++i) {
            int s0 = __shfl(sv, gbase + i);
            bf16x8 v0 = *(const bf16x8*)(T + (size_t)s0 * DD + j * 8);
#pragma unroll
            for (int q = 0; q < 8; ++q) acc[q] += (float)v0[q];
        }
    }
    const float inv = 1.0f / fmaxf((float)d, 1.0f);
    bf16x8 o;
#pragma unroll
    for (int q = 0; q < 8; ++q) o[q] = (__bf16)(acc[q] * inv);
    *(bf16x8*)(Agg + (size_t)node * DD + j * 8) = o;
}

// out = gelu([Xb, Agg] @ W2f + b2f); persistent-B: wave w holds W2f quarter
// (nt = 2w, 2w+1; 16 frags = 64 VGPR) for the WHOLE kernel — zero B reloads.
// Block's 4 waves = 4 quarters of the same tile (Xb/Agg L1-shared); tiles
// strided by gridDim; next tile's A-frags prefetched (named bufs, rule #20).
#define FFN2_LOAD(TT, XA, GA)                                              \
    {                                                                      \
        const size_t rb = (size_t)((TT) * 16 + c) * DD + kh * 8;           \
        _Pragma("unroll")                                                  \
        for (int q = 0; q < 4; ++q) {                                      \
            XA[q] = *(const bf16x8*)(Xb + rb + q * 32);                    \
            GA[q] = *(const bf16x8*)(Agg + rb + q * 32);                   \
        }                                                                  \
    }

#define FFN2_COMP(TT, XA, GA)                                              \
    {                                                                      \
        f32x4 acc0 = {}, acc1 = {};                                        \
        _Pragma("unroll")                                                  \
        for (int kt = 0; kt < 4; ++kt) {                                   \
            acc0 = __builtin_amdgcn_mfma_f32_16x16x32_bf16(XA[kt], Bf[kt][0], acc0, 0, 0, 0); \
            acc1 = __builtin_amdgcn_mfma_f32_16x16x32_bf16(XA[kt], Bf[kt][1], acc1, 0, 0, 0); \
        }                                                                  \
        _Pragma("unroll")                                                  \
        for (int kt = 0; kt < 4; ++kt) {                                   \
            acc0 = __builtin_amdgcn_mfma_f32_16x16x32_bf16(GA[kt], Bf[4 + kt][0], acc0, 0, 0, 0); \
            acc1 = __builtin_amdgcn_mfma_f32_16x16x32_bf16(GA[kt], Bf[4 + kt][1], acc1, 0, 0, 0); \
        }                                                                  \
        _Pragma("unroll")                                                  \
        for (int r = 0; r < 4; ++r) {                                      \
            int row = (TT) * 16 + kh * 4 + r;                              \
            out[(size_t)row * DD + (w * 2) * 16 + c] = gelu_fast(acc0[r] + bias0); \
            out[(size_t)row * DD + (w * 2 + 1) * 16 + c] = gelu_fast(acc1[r] + bias1); \
        }                                                                  \
    }

__global__ __launch_bounds__(256) void ffn2_kernel(
    const __bf16* __restrict__ Xb, const __bf16* __restrict__ Agg,
    const __bf16* __restrict__ W2f, const float* __restrict__ b2f,
    float* __restrict__ out)
{
    const int w = threadIdx.x >> 6;        // wave = quarter (nt 2w, 2w+1)
    const int lane = threadIdx.x & 63;
    const int c = lane & 15, kh = lane >> 4;
    const int G = gridDim.x;

    bf16x8 Bf[8][2];
#pragma unroll
    for (int kt = 0; kt < 8; ++kt) {
        Bf[kt][0] = *(const bf16x8*)(W2f + ((size_t)((kt * 8 + w * 2) * 64 + lane)) * 8);
        Bf[kt][1] = *(const bf16x8*)(W2f + ((size_t)((kt * 8 + w * 2 + 1) * 64 + lane)) * 8);
    }
    const float bias0 = b2f[(w * 2) * 16 + c];
    const float bias1 = b2f[(w * 2 + 1) * 16 + c];

    int tile = blockIdx.x;
    if (tile >= NTILE) return;
    bf16x8 xa[4], ga[4], xb2[4], gb[4];
    FFN2_LOAD(tile, xa, ga);
    while (true) {
        int t2 = tile + G;
        if (t2 < NTILE) FFN2_LOAD(t2, xb2, gb);
        FFN2_COMP(tile, xa, ga);
        if (t2 >= NTILE) break;
        int t3 = t2 + G;
        if (t3 < NTILE) FFN2_LOAD(t3, xa, ga);
        FFN2_COMP(t2, xb2, gb);
        if (t3 >= NTILE) break;
        tile = t3;
    }
}

extern "C" void kernel_launch(void* const* d_in, const int* in_sizes, int n_in,
                              void* d_out, int out_size, void* d_ws, size_t ws_size,
                              hipStream_t stream) {
    const float* node_repr = (const float*)d_in[0];
    const int*   edges     = (const int*)d_in[1];
    const float* g1 = (const float*)d_in[2];
    const float* be1 = (const float*)d_in[3];
    const float* m1 = (const float*)d_in[4];
    const float* v1 = (const float*)d_in[5];
    const float* W1 = (const float*)d_in[6];
    const float* b1 = (const float*)d_in[7];
    const float* g2 = (const float*)d_in[8];
    const float* be2 = (const float*)d_in[9];
    const float* m2 = (const float*)d_in[10];
    const float* v2 = (const float*)d_in[11];
    const float* W2 = (const float*)d_in[12];
    const float* b2 = (const float*)d_in[13];

    char* ws = (char*)d_ws;
    __bf16* W1f = (__bf16*)(ws + W1F_OFF);
    __bf16* W2f = (__bf16*)(ws + W2F_OFF);
    float* b1f = (float*)(ws + B1F_OFF);
    float* b2f = (float*)(ws + B2F_OFF);
    __bf16* T  = (__bf16*)(ws + T_OFF);
    int* offs  = (int*)(ws + OFFS_OFF);
    int* elist = (int*)(ws + ELIST_OFF);
    int* cntg  = (int*)(ws + CNTG_OFF);
    int* bofs  = (int*)(ws + BOFS_OFF);
    int* bsum  = (int*)(ws + BSUM_OFF);
    int* boff  = (int*)(ws + BOFF_OFF);
    __bf16* Agg = (__bf16*)(ws + AGG_OFF);
    int* pairbuf = (int*)(ws + AGG_OFF);
    __bf16* Xb = (__bf16*)(ws + XB_OFF);
    float* out = (float*)d_out;

    hipLaunchKernelGGL(prep_kernel, dim3(256 + NBLK), dim3(256), 0, stream,
                       g1, be1, m1, v1, W1, b1, g2, be2, m2, v2, W2, b2,
                       edges, W1f, W2f, b1f, b2f, cntg);

    hipLaunchKernelGGL(sortb_kernel, dim3(NBLK), dim3(256), 0, stream, cntg, bofs, bsum);
    hipLaunchKernelGGL(scan_top_kernel, dim3(1), dim3(512), 0, stream, bsum, boff);

    hipLaunchKernelGGL(sortc_ffn1_kernel, dim3(NBLK + (NTILE + 7) / 8), dim3(256), 0, stream,
                       edges, boff, bofs, pairbuf, node_repr, W1f, b1f, T, Xb);

    hipLaunchKernelGGL(p2_kernel, dim3(NBLK), dim3(256), 0, stream,
                       boff, pairbuf, elist, offs);

    hipLaunchKernelGGL(agg_kernel, dim3((NN * 16 + 255) / 256), dim3(256), 0, stream,
                       T, offs, elist, Agg);

    hipLaunchKernelGGL(ffn2_kernel, dim3(FFN2_BLKS), dim3(256), 0, stream,
                       Xb, Agg, W2f, b2f, out);
}

// Round 16
// 104.484 us; speedup vs baseline: 1.4015x; 1.0216x over previous
//
#include <hip/hip_runtime.h>

#define NN 100000
#define DD 128
#define EE 640000
#define BN_EPS 1e-3f
#define NBLK 391    // ceil(NN/256); #buckets and #sort blocks
#define NTILE 6250  // NN/16 exactly
#define EPB 1637    // edges per sort block: 391*1637 >= EE
#define FFN1_BLKS 782
#define FFN2_BLKS 768

typedef __bf16 bf16x8 __attribute__((ext_vector_type(8)));
typedef float f32x4 __attribute__((ext_vector_type(4)));

// ---- workspace byte offsets ----
#define W1F_OFF 0u
#define W2F_OFF 32768u
#define B1F_OFF 98304u
#define B2F_OFF 98816u
#define T_OFF   99328u
#define OFFS_OFF 26099328u    // NN+1 ints
#define ELIST_OFF 26899328u   // EE int; head aliases cntg+bofs (dead before p2)
#define CNTG_OFF ELIST_OFF               // 391*391 int
#define BOFS_OFF (ELIST_OFF + 611524u)   // 391*391 int
#define BSUM_OFF 29459328u
#define AGG_OFF 29464576u     // NN*128 bf16; aliases pairbuf (EE int) before agg runs
#define XB_OFF  55064576u     // NN*128 bf16

// tanh-form gelu; max |err| vs exact ~3e-4 (threshold 9.8e-2)
__device__ __forceinline__ float gelu_fast(float x) {
    float x3 = x * x * x;
    float z2 = 1.5957691216057308f * x + 0.07135481627002407f * x3;
    return x / (1.0f + __expf(-z2));
}

// prep: [0,64) fold_bias | [64,256) fold_w | [256,647) sortA per-slice bucket counts
__global__ __launch_bounds__(256) void prep_kernel(
    const float* __restrict__ g1, const float* __restrict__ be1,
    const float* __restrict__ m1, const float* __restrict__ v1,
    const float* __restrict__ W1, const float* __restrict__ b1,
    const float* __restrict__ g2, const float* __restrict__ be2,
    const float* __restrict__ m2, const float* __restrict__ v2,
    const float* __restrict__ W2, const float* __restrict__ b2,
    const int* __restrict__ edges,
    __bf16* __restrict__ W1f, __bf16* __restrict__ W2f,
    float* __restrict__ b1f, float* __restrict__ b2f,
    int* __restrict__ cntg)
{
    const int blk = blockIdx.x;
    const int t = threadIdx.x;
    if (blk < 64) {
        const int w = (blk * 256 + t) >> 6;
        const int lane = t & 63;
        if (w < 128) {
            float acc = 0.f;
            for (int k = lane; k < 128; k += 64) {
                float s = g1[k] * rsqrtf(v1[k] + BN_EPS);
                float sh = be1[k] - m1[k] * s;
                acc += sh * W1[k * 128 + w];
            }
#pragma unroll
            for (int off = 32; off > 0; off >>= 1) acc += __shfl_down(acc, off);
            if (lane == 0) b1f[w] = acc + b1[w];
        } else {
            const int n = w - 128;
            float acc = 0.f;
            for (int k = lane; k < 256; k += 64) {
                float s = g2[k] * rsqrtf(v2[k] + BN_EPS);
                float sh = be2[k] - m2[k] * s;
                acc += sh * W2[k * 128 + n];
            }
#pragma unroll
            for (int off = 32; off > 0; off >>= 1) acc += __shfl_down(acc, off);
            if (lane == 0) b2f[n] = acc + b2[n];
        }
    } else if (blk < 256) {
        int tid = (blk - 64) * 256 + t;
        if (tid < 16384) {
            int idx = tid;
            int i = idx & 7, l = (idx >> 3) & 63, nt = (idx >> 9) & 7, kt = idx >> 12;
            int k = kt * 32 + (l >> 4) * 8 + i;
            int n = nt * 16 + (l & 15);
            float s = g1[k] * rsqrtf(v1[k] + BN_EPS);
            W1f[idx] = (__bf16)(s * W1[k * 128 + n]);
        } else {
            int idx = tid - 16384;
            int i = idx & 7, l = (idx >> 3) & 63, nt = (idx >> 9) & 7, kt = idx >> 12;
            int n = nt * 16 + (l & 15);
            int row;
            if (kt < 4) {
                row = kt * 32 + (l >> 4) * 8 + i;
            } else {
                int q = (kt - 4) * 32 + (l >> 4) * 8 + i;
                row = 128 + ((q & 7) * 16 + (q >> 3));
            }
            float s = g2[row] * rsqrtf(v2[row] + BN_EPS);
            W2f[idx] = (__bf16)(s * W2[row * 128 + n]);
        }
    } else {
        __shared__ int cnt[NBLK];
        const int k = blk - 256;
        for (int b = t; b < NBLK; b += 256) cnt[b] = 0;
        __syncthreads();
        const int e0 = k * EPB, e1 = min(e0 + EPB, EE);
        for (int e = e0 + t; e < e1; e += 256)
            atomicAdd(&cnt[edges[e] >> 8], 1);
        __syncthreads();
        for (int b = t; b < NBLK; b += 256) cntg[k * NBLK + b] = cnt[b];
    }
}

// sortB: bucket b; exclusive scan of cntg[k][b] over k -> bofs; total -> bsum[b]
__global__ __launch_bounds__(256) void sortb_kernel(const int* __restrict__ cntg,
                                                    int* __restrict__ bofs,
                                                    int* __restrict__ bsum)
{
    const int b = blockIdx.x, t = threadIdx.x;
    __shared__ int sp[256];
    int ia = 2 * t, ib = 2 * t + 1;
    int va = (ia < NBLK) ? cntg[ia * NBLK + b] : 0;
    int vb = (ib < NBLK) ? cntg[ib * NBLK + b] : 0;
    sp[t] = va + vb;
    __syncthreads();
    for (int off = 1; off < 256; off <<= 1) {
        int tmp = (t >= off) ? sp[t - off] : 0;
        __syncthreads();
        sp[t] += tmp;
        __syncthreads();
    }
    int pexcl = sp[t] - (va + vb);
    if (ia < NBLK) bofs[b * NBLK + ia] = pexcl;
    if (ib < NBLK) bofs[b * NBLK + ib] = pexcl + va;
    if (t == 255) bsum[b] = sp[255];
}

// sortC: inline exclusive scan of bsum (no scan_top kernel) seeds LDS cursors;
// scatter this block's edge slice into bucket-sorted pairbuf.
__global__ __launch_bounds__(256) void sortc_kernel(const int* __restrict__ edges,
                                                    const int* __restrict__ bsum,
                                                    const int* __restrict__ bofs,
                                                    int* __restrict__ pairbuf)
{
    __shared__ int sp[256];
    __shared__ int cur[NBLK];
    const int k = blockIdx.x, t = threadIdx.x;
    int ia = 2 * t, ib = 2 * t + 1;
    int va = (ia < NBLK) ? bsum[ia] : 0;
    int vb = (ib < NBLK) ? bsum[ib] : 0;
    sp[t] = va + vb;
    __syncthreads();
    for (int off = 1; off < 256; off <<= 1) {
        int tmp = (t >= off) ? sp[t - off] : 0;
        __syncthreads();
        sp[t] += tmp;
        __syncthreads();
    }
    int pexcl = sp[t] - (va + vb);
    if (ia < NBLK) cur[ia] = pexcl + bofs[ia * NBLK + k];
    if (ib < NBLK) cur[ib] = pexcl + va + bofs[ib * NBLK + k];
    __syncthreads();
    const int e0 = k * EPB, e1 = min(e0 + EPB, EE);
    for (int e = e0 + t; e < e1; e += 256) {
        int dst = edges[e];
        int src = edges[EE + e];
        int pos = atomicAdd(&cur[dst >> 8], 1);
        pairbuf[pos] = (src << 8) | (dst & 255);
    }
}

// fused: [0,NBLK) p2 (bucket-local CSR finalize; base via bsum reduction) |
// [NBLK, NBLK+782) ffn1 (W1f in 32 KB LDS, 8 tiles/block, 2-tile X pipeline).
__global__ __launch_bounds__(256) void p2_ffn1_kernel(
    const int* __restrict__ bsum, const int* __restrict__ pairbuf,
    int* __restrict__ elist, int* __restrict__ offs,
    const float* __restrict__ X, const __bf16* __restrict__ W1f,
    const float* __restrict__ b1f, __bf16* __restrict__ T,
    __bf16* __restrict__ Xb)
{
    __shared__ __bf16 sW[16384];   // ffn1: weight stage; p2: aliased int arrays
    const int t = threadIdx.x;
    if (blockIdx.x < NBLK) {
        int* sArr = (int*)sW;        // 256
        int* cur  = sArr + 256;      // 256
        int* red  = sArr + 512;      // 4
        const int b = blockIdx.x;
        int part = 0;
        for (int i = t; i < b; i += 256) part += bsum[i];
#pragma unroll
        for (int off = 32; off > 0; off >>= 1) part += __shfl_down(part, off);
        if ((t & 63) == 0) red[t >> 6] = part;
        cur[t] = 0;
        __syncthreads();
        const int start = red[0] + red[1] + red[2] + red[3];
        const int end = start + bsum[b];
        for (int e = start + t; e < end; e += 256)
            atomicAdd(&cur[pairbuf[e] & 255], 1);
        __syncthreads();
        int v = cur[t];
        sArr[t] = v;
        __syncthreads();
        for (int off = 1; off < 256; off <<= 1) {
            int tmp = (t >= off) ? sArr[t - off] : 0;
            __syncthreads();
            sArr[t] += tmp;
            __syncthreads();
        }
        int ex = sArr[t] - v + start;
        const int node = b * 256 + t;
        if (node <= NN) offs[node] = ex;   // node==NN -> sentinel EE
        __syncthreads();
        cur[t] = ex;
        __syncthreads();
        for (int e = start + t; e < end; e += 256) {
            int item = pairbuf[e];
            int pos = atomicAdd(&cur[item & 255], 1);
            elist[pos] = item >> 8;
        }
        return;
    }
#pragma unroll
    for (int i = 0; i < 8; ++i) {
        int ch = i * 256 + t;
        *(bf16x8*)(sW + ch * 8) = *(const bf16x8*)(W1f + (size_t)ch * 8);
    }
    __syncthreads();

    const int wave = t >> 6;
    const int lane = t & 63;
    const int c = lane & 15, kh = lane >> 4;
    const int tbase = (blockIdx.x - NBLK) * 8;
    const int tile0 = tbase + wave;
    const int tile1 = tbase + 4 + wave;

    float bias[8];
#pragma unroll
    for (int nt = 0; nt < 8; ++nt) bias[nt] = b1f[nt * 16 + c];

    f32x4 r0[4], r1[4], s0[4], s1[4];
    bf16x8 af[4];

    if (tile0 < NTILE) {
        const float* xr = X + (size_t)(tile0 * 16 + c) * DD + kh * 8;
#pragma unroll
        for (int q = 0; q < 4; ++q) {
            r0[q] = *(const f32x4*)(xr + q * 32);
            r1[q] = *(const f32x4*)(xr + q * 32 + 4);
        }
    }
    if (tile1 < NTILE) {   // in flight during tile0's convert/MFMA/stores
        const float* xr = X + (size_t)(tile1 * 16 + c) * DD + kh * 8;
#pragma unroll
        for (int q = 0; q < 4; ++q) {
            s0[q] = *(const f32x4*)(xr + q * 32);
            s1[q] = *(const f32x4*)(xr + q * 32 + 4);
        }
    }

    if (tile0 < NTILE) {
        const size_t rowb = (size_t)(tile0 * 16 + c) * DD;
#pragma unroll
        for (int kt = 0; kt < 4; ++kt) {
            bf16x8 fa;
#pragma unroll
            for (int i = 0; i < 4; ++i) { fa[i] = (__bf16)r0[kt][i]; fa[4 + i] = (__bf16)r1[kt][i]; }
            af[kt] = fa;
            *(bf16x8*)(Xb + rowb + kt * 32 + kh * 8) = fa;
        }
        f32x4 acc[8] = {};
#pragma unroll
        for (int kt = 0; kt < 4; ++kt)
#pragma unroll
            for (int nt = 0; nt < 8; ++nt) {
                bf16x8 bfr = *(const bf16x8*)(sW + ((kt * 8 + nt) * 64 + lane) * 8);
                acc[nt] = __builtin_amdgcn_mfma_f32_16x16x32_bf16(af[kt], bfr, acc[nt], 0, 0, 0);
            }
#pragma unroll
        for (int r = 0; r < 4; ++r) {
            int row = tile0 * 16 + kh * 4 + r;
            bf16x8 o;
#pragma unroll
            for (int nt = 0; nt < 8; ++nt)
                o[nt] = (__bf16)gelu_fast(acc[nt][r] + bias[nt]);
            *(bf16x8*)(T + (size_t)row * DD + c * 8) = o;
        }
    }
    if (tile1 < NTILE) {
        const size_t rowb = (size_t)(tile1 * 16 + c) * DD;
#pragma unroll
        for (int kt = 0; kt < 4; ++kt) {
            bf16x8 fa;
#pragma unroll
            for (int i = 0; i < 4; ++i) { fa[i] = (__bf16)s0[kt][i]; fa[4 + i] = (__bf16)s1[kt][i]; }
            af[kt] = fa;
            *(bf16x8*)(Xb + rowb + kt * 32 + kh * 8) = fa;
        }
        f32x4 acc[8] = {};
#pragma unroll
        for (int kt = 0; kt < 4; ++kt)
#pragma unroll
            for (int nt = 0; nt < 8; ++nt) {
                bf16x8 bfr = *(const bf16x8*)(sW + ((kt * 8 + nt) * 64 + lane) * 8);
                acc[nt] = __builtin_amdgcn_mfma_f32_16x16x32_bf16(af[kt], bfr, acc[nt], 0, 0, 0);
            }
#pragma unroll
        for (int r = 0; r < 4; ++r) {
            int row = tile1 * 16 + kh * 4 + r;
            bf16x8 o;
#pragma unroll
            for (int nt = 0; nt < 8; ++nt)
                o[nt] = (__bf16)gelu_fast(acc[nt][r] + bias[nt]);
            *(bf16x8*)(T + (size_t)row * DD + c * 8) = o;
        }
    }
}

// gather-mean: 16 threads/node; coalesced elist load + __shfl broadcast
__global__ __launch_bounds__(256) void agg_kernel(
    const __bf16* __restrict__ T, const int* __restrict__ offs,
    const int* __restrict__ elist, __bf16* __restrict__ Agg)
{
    int t = blockIdx.x * 256 + threadIdx.x;
    int node = t >> 4, j = t & 15;
    if (node >= NN) return;
    const int lane = threadIdx.x & 63;
    const int gbase = lane & 48;
    const int beg = offs[node];
    const int end = offs[node + 1];
    const int d = end - beg;
    float acc[8] = {};
    for (int eb = beg; eb < end; eb += 16) {
        int me = eb + (lane & 15);
        int sv = (me < end) ? elist[me] : 0;
        int cnt = min(end - eb, 16);
        int i = 0;
        for (; i + 3 < cnt; i += 4) {
            int s0 = __shfl(sv, gbase + i);
            int s1 = __shfl(sv, gbase + i + 1);
            int s2 = __shfl(sv, gbase + i + 2);
            int s3 = __shfl(sv, gbase + i + 3);
            bf16x8 v0 = *(const bf16x8*)(T + (size_t)s0 * DD + j * 8);
            bf16x8 v1 = *(const bf16x8*)(T + (size_t)s1 * DD + j * 8);
            bf16x8 v2 = *(const bf16x8*)(T + (size_t)s2 * DD + j * 8);
            bf16x8 v3 = *(const bf16x8*)(T + (size_t)s3 * DD + j * 8);
#pragma unroll
            for (int q = 0; q < 8; ++q)
                acc[q] += ((float)v0[q] + (float)v1[q]) + ((float)v2[q] + (float)v3[q]);
        }
        for (; i < cnt; ++i) {
            int s0 = __shfl(sv, gbase + i);
            bf16x8 v0 = *(const bf16x8*)(T + (size_t)s0 * DD + j * 8);
#pragma unroll
            for (int q = 0; q < 8; ++q) acc[q] += (float)v0[q];
        }
    }
    const float inv = 1.0f / fmaxf((float)d, 1.0f);
    bf16x8 o;
#pragma unroll
    for (int q = 0; q < 8; ++q) o[q] = (__bf16)(acc[q] * inv);
    *(bf16x8*)(Agg + (size_t)node * DD + j * 8) = o;
}

// out = gelu([Xb, Agg] @ W2f + b2f); persistent-B quarters, grid-stride tiles,
// next-tile A prefetch (named buffers).
#define FFN2_LOAD(TT, XA, GA)                                              \
    {                                                                      \
        const size_t rb = (size_t)((TT) * 16 + c) * DD + kh * 8;           \
        _Pragma("unroll")                                                  \
        for (int q = 0; q < 4; ++q) {                                      \
            XA[q] = *(const bf16x8*)(Xb + rb + q * 32);                    \
            GA[q] = *(const bf16x8*)(Agg + rb + q * 32);                   \
        }                                                                  \
    }

#define FFN2_COMP(TT, XA, GA)                                              \
    {                                                                      \
        f32x4 acc0 = {}, acc1 = {};                                        \
        _Pragma("unroll")                                                  \
        for (int kt = 0; kt < 4; ++kt) {                                   \
            acc0 = __builtin_amdgcn_mfma_f32_16x16x32_bf16(XA[kt], Bf[kt][0], acc0, 0, 0, 0); \
            acc1 = __builtin_amdgcn_mfma_f32_16x16x32_bf16(XA[kt], Bf[kt][1], acc1, 0, 0, 0); \
        }                                                                  \
        _Pragma("unroll")                                                  \
        for (int kt = 0; kt < 4; ++kt) {                                   \
            acc0 = __builtin_amdgcn_mfma_f32_16x16x32_bf16(GA[kt], Bf[4 + kt][0], acc0, 0, 0, 0); \
            acc1 = __builtin_amdgcn_mfma_f32_16x16x32_bf16(GA[kt], Bf[4 + kt][1], acc1, 0, 0, 0); \
        }                                                                  \
        _Pragma("unroll")                                                  \
        for (int r = 0; r < 4; ++r) {                                      \
            int row = (TT) * 16 + kh * 4 + r;                              \
            out[(size_t)row * DD + (w * 2) * 16 + c] = gelu_fast(acc0[r] + bias0); \
            out[(size_t)row * DD + (w * 2 + 1) * 16 + c] = gelu_fast(acc1[r] + bias1); \
        }                                                                  \
    }

__global__ __launch_bounds__(256) void ffn2_kernel(
    const __bf16* __restrict__ Xb, const __bf16* __restrict__ Agg,
    const __bf16* __restrict__ W2f, const float* __restrict__ b2f,
    float* __restrict__ out)
{
    const int w = threadIdx.x >> 6;        // wave = quarter (nt 2w, 2w+1)
    const int lane = threadIdx.x & 63;
    const int c = lane & 15, kh = lane >> 4;
    const int G = gridDim.x;

    bf16x8 Bf[8][2];
#pragma unroll
    for (int kt = 0; kt < 8; ++kt) {
        Bf[kt][0] = *(const bf16x8*)(W2f + ((size_t)((kt * 8 + w * 2) * 64 + lane)) * 8);
        Bf[kt][1] = *(const bf16x8*)(W2f + ((size_t)((kt * 8 + w * 2 + 1) * 64 + lane)) * 8);
    }
    const float bias0 = b2f[(w * 2) * 16 + c];
    const float bias1 = b2f[(w * 2 + 1) * 16 + c];

    int tile = blockIdx.x;
    if (tile >= NTILE) return;
    bf16x8 xa[4], ga[4], xb2[4], gb[4];
    FFN2_LOAD(tile, xa, ga);
    while (true) {
        int t2 = tile + G;
        if (t2 < NTILE) FFN2_LOAD(t2, xb2, gb);
        FFN2_COMP(tile, xa, ga);
        if (t2 >= NTILE) break;
        int t3 = t2 + G;
        if (t3 < NTILE) FFN2_LOAD(t3, xa, ga);
        FFN2_COMP(t2, xb2, gb);
        if (t3 >= NTILE) break;
        tile = t3;
    }
}

extern "C" void kernel_launch(void* const* d_in, const int* in_sizes, int n_in,
                              void* d_out, int out_size, void* d_ws, size_t ws_size,
                              hipStream_t stream) {
    const float* node_repr = (const float*)d_in[0];
    const int*   edges     = (const int*)d_in[1];
    const float* g1 = (const float*)d_in[2];
    const float* be1 = (const float*)d_in[3];
    const float* m1 = (const float*)d_in[4];
    const float* v1 = (const float*)d_in[5];
    const float* W1 = (const float*)d_in[6];
    const float* b1 = (const float*)d_in[7];
    const float* g2 = (const float*)d_in[8];
    const float* be2 = (const float*)d_in[9];
    const float* m2 = (const float*)d_in[10];
    const float* v2 = (const float*)d_in[11];
    const float* W2 = (const float*)d_in[12];
    const float* b2 = (const float*)d_in[13];

    char* ws = (char*)d_ws;
    __bf16* W1f = (__bf16*)(ws + W1F_OFF);
    __bf16* W2f = (__bf16*)(ws + W2F_OFF);
    float* b1f = (float*)(ws + B1F_OFF);
    float* b2f = (float*)(ws + B2F_OFF);
    __bf16* T  = (__bf16*)(ws + T_OFF);
    int* offs  = (int*)(ws + OFFS_OFF);
    int* elist = (int*)(ws + ELIST_OFF);
    int* cntg  = (int*)(ws + CNTG_OFF);
    int* bofs  = (int*)(ws + BOFS_OFF);
    int* bsum  = (int*)(ws + BSUM_OFF);
    __bf16* Agg = (__bf16*)(ws + AGG_OFF);
    int* pairbuf = (int*)(ws + AGG_OFF);
    __bf16* Xb = (__bf16*)(ws + XB_OFF);
    float* out = (float*)d_out;

    hipLaunchKernelGGL(prep_kernel, dim3(256 + NBLK), dim3(256), 0, stream,
                       g1, be1, m1, v1, W1, b1, g2, be2, m2, v2, W2, b2,
                       edges, W1f, W2f, b1f, b2f, cntg);

    hipLaunchKernelGGL(sortb_kernel, dim3(NBLK), dim3(256), 0, stream, cntg, bofs, bsum);

    hipLaunchKernelGGL(sortc_kernel, dim3(NBLK), dim3(256), 0, stream,
                       edges, bsum, bofs, pairbuf);

    hipLaunchKernelGGL(p2_ffn1_kernel, dim3(NBLK + FFN1_BLKS), dim3(256), 0, stream,
                       bsum, pairbuf, elist, offs, node_repr, W1f, b1f, T, Xb);

    hipLaunchKernelGGL(agg_kernel, dim3((NN * 16 + 255) / 256), dim3(256), 0, stream,
                       T, offs, elist, Agg);

    hipLaunchKernelGGL(ffn2_kernel, dim3(FFN2_BLKS), dim3(256), 0, stream,
                       Xb, Agg, W2f, b2f, out);
}